// Round 16
// baseline (4624.895 us; speedup 1.0000x reference)
//
#include <hip/hip_runtime.h>
#include <math.h>

// LSTM B=128,T=1024,D=64,H=256,C=6 — R16: 2 batches per block, weights shared.
//
// R15 accounting: VALU 1860cy + LDS ~3000cy per step/CU, measured 6900cy ->
// per-wave serialization, and 2 waves/SIMD is PROVEN impossible (Wh f16 =
// 512KB = entire CU register file; R11 spill). Only lever left: ILP via a
// second batch stream on the SAME weights:
//  * 64 blocks x 2 batches; tail-LDS reads SHARED (1x per thread, dotted vs
//    both h streams); AGPR read:dot ratio 1:2 -> 1:4
//  * two independent dot chains interleave -> fill latency slots
//  * V audit: 128 wV + 16 hs + 16 qbank + 32 tw + 8 acc + 16 xg + misc ~= 243
//  * xg_gemm: wsl reads vectorized to float4 (2112 -> 576 LDS instr/thread)
// Numerics identical to R8-R15 (f16 weights/h/xg, fp32 accum): absmax 3.9e-3.

#define Tt 1024
#define Dd 64
#define Hh 256
#define G4 1024
#define Cc 6
#define BT (128 * 1024)
#define XG_BYTES ((size_t)BT * G4 * 2)   // 256 MB f16

typedef _Float16 f16x2 __attribute__((ext_vector_type(2)));

__device__ __forceinline__ float dot2(f16x2 a, f16x2 b, float c) {
#if __has_builtin(__builtin_amdgcn_fdot2)
    return __builtin_amdgcn_fdot2(a, b, c, false);
#else
    return c + (float)a.x * (float)b.x + (float)a.y * (float)b.y;
#endif
}
__device__ __forceinline__ float sigm(float p) { return 1.0f / (1.0f + __expf(-p)); }
__device__ __forceinline__ float tanh_fast(float p) {
    return 1.0f - 2.0f / (__expf(2.0f * p) + 1.0f);
}
__device__ __forceinline__ unsigned short f2h(float v) {
    _Float16 h = (_Float16)v;
    return __builtin_bit_cast(unsigned short, h);
}
__device__ __forceinline__ float h2f(unsigned short u) {
    return (float)__builtin_bit_cast(_Float16, u);
}
__device__ __forceinline__ f16x2 bcf(float v) { return __builtin_bit_cast(f16x2, v); }
__device__ __forceinline__ f16x2 bcu(unsigned int v) { return __builtin_bit_cast(f16x2, v); }
__device__ __forceinline__ unsigned int packh(float a, float b) {
    return (unsigned int)f2h(a) | ((unsigned int)f2h(b) << 16);
}

// ---------------- stage 1: xg = x @ Wx + bias, f16 (float4 LDS reads) ------
__global__ __launch_bounds__(256) void xg_gemm(
    const float* __restrict__ x, const float* __restrict__ Wx,
    const float* __restrict__ bias, unsigned short* __restrict__ xg)
{
    __shared__ float xs[32][65];
    __shared__ float wsl[64][256];

    const int tid = threadIdx.x;
    const long r0 = (long)blockIdx.x * 32;
    const int  c0 = blockIdx.y * 256;

    {
        const float4* src = (const float4*)(x + r0 * Dd);
        float4 v0 = src[tid], v1 = src[tid + 256];
        int e = tid * 4;
        xs[e >> 6][e & 63] = v0.x; xs[e >> 6][(e & 63) + 1] = v0.y;
        xs[e >> 6][(e & 63) + 2] = v0.z; xs[e >> 6][(e & 63) + 3] = v0.w;
        e += 1024;
        xs[e >> 6][e & 63] = v1.x; xs[e >> 6][(e & 63) + 1] = v1.y;
        xs[e >> 6][(e & 63) + 2] = v1.z; xs[e >> 6][(e & 63) + 3] = v1.w;
    }
    for (int i = tid; i < 64 * 64; i += 256) {
        int d = i >> 6, cq = i & 63;
        *(float4*)&wsl[d][cq * 4] = *(const float4*)(Wx + (long)d * G4 + c0 + cq * 4);
    }
    __syncthreads();

    const int r = tid & 31, cg = tid >> 5;
    float acc[32];
    #pragma unroll
    for (int c = 0; c < 32; ++c) acc[c] = bias[c0 + cg * 32 + c];
    for (int k = 0; k < 64; ++k) {
        float xv = xs[r][k];
        const float4* wr = (const float4*)&wsl[k][cg * 32];
        #pragma unroll
        for (int c4 = 0; c4 < 8; ++c4) {
            float4 wv = wr[c4];
            acc[4*c4+0] += xv * wv.x; acc[4*c4+1] += xv * wv.y;
            acc[4*c4+2] += xv * wv.z; acc[4*c4+3] += xv * wv.w;
        }
    }
    unsigned int ow[16];
    #pragma unroll
    for (int c2 = 0; c2 < 16; ++c2)
        ow[c2] = packh(acc[2 * c2], acc[2 * c2 + 1]);
    uint4* dst = (uint4*)(xg + (r0 + r) * G4 + c0 + cg * 32);
    dst[0] = make_uint4(ow[0], ow[1], ow[2], ow[3]);
    dst[1] = make_uint4(ow[4], ow[5], ow[6], ow[7]);
    dst[2] = make_uint4(ow[8], ow[9], ow[10], ow[11]);
    dst[3] = make_uint4(ow[12], ow[13], ow[14], ow[15]);
}

// ---------------- stage 2: recurrence, 2 batches/block ---------------------
// pair i covers k = 2i,2i+1; cols A,B,C,D = gates i,f,g,o of unit tid.

#define WLOADV4(i) \
  const f16x2 wA_##i = f16x2{(_Float16)Wh[(2*(i))*G4 + colA], (_Float16)Wh[(2*(i)+1)*G4 + colA]}; \
  const f16x2 wB_##i = f16x2{(_Float16)Wh[(2*(i))*G4 + colB], (_Float16)Wh[(2*(i)+1)*G4 + colB]}; \
  const f16x2 wC_##i = f16x2{(_Float16)Wh[(2*(i))*G4 + colC], (_Float16)Wh[(2*(i)+1)*G4 + colC]}; \
  const f16x2 wD_##i = f16x2{(_Float16)Wh[(2*(i))*G4 + colD], (_Float16)Wh[(2*(i)+1)*G4 + colD]};

#define AW1(dst, cix, i) { \
    f16x2 t_ = f16x2{(_Float16)Wh[(2*(i))*G4 + (cix)], (_Float16)Wh[(2*(i)+1)*G4 + (cix)]}; \
    asm volatile("v_accvgpr_write_b32 %0, %1" : "=a"(dst) : "v"(__builtin_bit_cast(float, t_))); }

#define WLOADA4(i) \
  float awA_##i, awB_##i, awC_##i, awD_##i; \
  AW1(awA_##i, colA, i) AW1(awB_##i, colB, i) \
  AW1(awC_##i, colC, i) AW1(awD_##i, colD, i)

#define REPV32(M) \
  M(0) M(1) M(2) M(3) M(4) M(5) M(6) M(7) \
  M(8) M(9) M(10) M(11) M(12) M(13) M(14) M(15) \
  M(16) M(17) M(18) M(19) M(20) M(21) M(22) M(23) \
  M(24) M(25) M(26) M(27) M(28) M(29) M(30) M(31)

#define REPA64(M) \
  M(32) M(33) M(34) M(35) M(36) M(37) M(38) M(39) \
  M(40) M(41) M(42) M(43) M(44) M(45) M(46) M(47) \
  M(48) M(49) M(50) M(51) M(52) M(53) M(54) M(55) \
  M(56) M(57) M(58) M(59) M(60) M(61) M(62) M(63) \
  M(64) M(65) M(66) M(67) M(68) M(69) M(70) M(71) \
  M(72) M(73) M(74) M(75) M(76) M(77) M(78) M(79) \
  M(80) M(81) M(82) M(83) M(84) M(85) M(86) M(87) \
  M(88) M(89) M(90) M(91) M(92) M(93) M(94) M(95)

// dot V-weight pair i against both batch streams
#define DOTP2(i, hp, hq) { f16x2 hp_ = (hp), hq_ = (hq); \
    aA0 = dot2(hp_, wA_##i, aA0); aB0 = dot2(hp_, wB_##i, aB0); \
    aC0 = dot2(hp_, wC_##i, aC0); aD0 = dot2(hp_, wD_##i, aD0); \
    aA1 = dot2(hq_, wA_##i, aA1); aB1 = dot2(hq_, wB_##i, aB1); \
    aC1 = dot2(hq_, wC_##i, aC1); aD1 = dot2(hq_, wD_##i, aD1); }

// V group: 4 pairs x 2 batches; then rotate both h slots to group n
#define GV2(sp, sq, n, i0,i1,i2,i3) { \
    DOTP2(i0, bcf(sp.x), bcf(sq.x)) DOTP2(i1, bcf(sp.y), bcf(sq.y)) \
    DOTP2(i2, bcf(sp.z), bcf(sq.z)) DOTP2(i3, bcf(sp.w), bcf(sq.w)) \
    sp = hv0[n]; sq = hv1[n]; }

#define ARD(dst, src) \
    asm volatile("v_accvgpr_read_b32 %0, %1" : "=v"(dst) : "a"(src));

// read 4 pairs' AGPR weights into the single qbank (16 temps)
#define AREADG1(i0,i1,i2,i3) \
    ARD(qA_0, awA_##i0) ARD(qB_0, awB_##i0) ARD(qC_0, awC_##i0) ARD(qD_0, awD_##i0) \
    ARD(qA_1, awA_##i1) ARD(qB_1, awB_##i1) ARD(qC_1, awC_##i1) ARD(qD_1, awD_##i1) \
    ARD(qA_2, awA_##i2) ARD(qB_2, awB_##i2) ARD(qC_2, awC_##i2) ARD(qD_2, awD_##i2) \
    ARD(qA_3, awA_##i3) ARD(qB_3, awB_##i3) ARD(qC_3, awC_##i3) ARD(qD_3, awD_##i3)

// dot qbank against both streams (pair j <-> component j); rotate slots
#define ADOTG2(sp, sq, n) { \
    f16x2 p0 = bcf(sp.x), p1 = bcf(sp.y), p2 = bcf(sp.z), p3 = bcf(sp.w); \
    f16x2 q0 = bcf(sq.x), q1 = bcf(sq.y), q2 = bcf(sq.z), q3 = bcf(sq.w); \
    aA0 = dot2(p0, bcf(qA_0), aA0); aB0 = dot2(p0, bcf(qB_0), aB0); \
    aC0 = dot2(p0, bcf(qC_0), aC0); aD0 = dot2(p0, bcf(qD_0), aD0); \
    aA1 = dot2(q0, bcf(qA_0), aA1); aB1 = dot2(q0, bcf(qB_0), aB1); \
    aC1 = dot2(q0, bcf(qC_0), aC1); aD1 = dot2(q0, bcf(qD_0), aD1); \
    aA0 = dot2(p1, bcf(qA_1), aA0); aB0 = dot2(p1, bcf(qB_1), aB0); \
    aC0 = dot2(p1, bcf(qC_1), aC0); aD0 = dot2(p1, bcf(qD_1), aD0); \
    aA1 = dot2(q1, bcf(qA_1), aA1); aB1 = dot2(q1, bcf(qB_1), aB1); \
    aC1 = dot2(q1, bcf(qC_1), aC1); aD1 = dot2(q1, bcf(qD_1), aD1); \
    aA0 = dot2(p2, bcf(qA_2), aA0); aB0 = dot2(p2, bcf(qB_2), aB0); \
    aC0 = dot2(p2, bcf(qC_2), aC0); aD0 = dot2(p2, bcf(qD_2), aD0); \
    aA1 = dot2(q2, bcf(qA_2), aA1); aB1 = dot2(q2, bcf(qB_2), aB1); \
    aC1 = dot2(q2, bcf(qC_2), aC1); aD1 = dot2(q2, bcf(qD_2), aD1); \
    aA0 = dot2(p3, bcf(qA_3), aA0); aB0 = dot2(p3, bcf(qB_3), aB0); \
    aC0 = dot2(p3, bcf(qC_3), aC0); aD0 = dot2(p3, bcf(qD_3), aD0); \
    aA1 = dot2(q3, bcf(qA_3), aA1); aB1 = dot2(q3, bcf(qB_3), aB1); \
    aC1 = dot2(q3, bcf(qC_3), aC1); aD1 = dot2(q3, bcf(qD_3), aD1); \
    sp = hv0[n]; sq = hv1[n]; }

// tail-weight double-buffer load (slot token s = 0/1)
#define TWL(s, jq) { twA##s = wl4[jq][colA]; twB##s = wl4[jq][colB]; \
                     twC##s = wl4[jq][colC]; twD##s = wl4[jq][colD]; }

// tail group vs both streams from tw slot s (no rotation variant below)
#define GT2_CORE(sp, sq, s) { \
    f16x2 p0 = bcf(sp.x), p1 = bcf(sp.y), p2 = bcf(sp.z), p3 = bcf(sp.w); \
    f16x2 q0 = bcf(sq.x), q1 = bcf(sq.y), q2 = bcf(sq.z), q3 = bcf(sq.w); \
    aA0 = dot2(p0, bcu(twA##s.x), aA0); aA0 = dot2(p1, bcu(twA##s.y), aA0); \
    aA0 = dot2(p2, bcu(twA##s.z), aA0); aA0 = dot2(p3, bcu(twA##s.w), aA0); \
    aB0 = dot2(p0, bcu(twB##s.x), aB0); aB0 = dot2(p1, bcu(twB##s.y), aB0); \
    aB0 = dot2(p2, bcu(twB##s.z), aB0); aB0 = dot2(p3, bcu(twB##s.w), aB0); \
    aC0 = dot2(p0, bcu(twC##s.x), aC0); aC0 = dot2(p1, bcu(twC##s.y), aC0); \
    aC0 = dot2(p2, bcu(twC##s.z), aC0); aC0 = dot2(p3, bcu(twC##s.w), aC0); \
    aD0 = dot2(p0, bcu(twD##s.x), aD0); aD0 = dot2(p1, bcu(twD##s.y), aD0); \
    aD0 = dot2(p2, bcu(twD##s.z), aD0); aD0 = dot2(p3, bcu(twD##s.w), aD0); \
    aA1 = dot2(q0, bcu(twA##s.x), aA1); aA1 = dot2(q1, bcu(twA##s.y), aA1); \
    aA1 = dot2(q2, bcu(twA##s.z), aA1); aA1 = dot2(q3, bcu(twA##s.w), aA1); \
    aB1 = dot2(q0, bcu(twB##s.x), aB1); aB1 = dot2(q1, bcu(twB##s.y), aB1); \
    aB1 = dot2(q2, bcu(twB##s.z), aB1); aB1 = dot2(q3, bcu(twB##s.w), aB1); \
    aC1 = dot2(q0, bcu(twC##s.x), aC1); aC1 = dot2(q1, bcu(twC##s.y), aC1); \
    aC1 = dot2(q2, bcu(twC##s.z), aC1); aC1 = dot2(q3, bcu(twC##s.w), aC1); \
    aD1 = dot2(q0, bcu(twD##s.x), aD1); aD1 = dot2(q1, bcu(twD##s.y), aD1); \
    aD1 = dot2(q2, bcu(twD##s.z), aD1); aD1 = dot2(q3, bcu(twD##s.w), aD1); }

#define GT2(sp, sq, s, n) { GT2_CORE(sp, sq, s) sp = hv0[n]; sq = hv1[n]; }
#define GT2_NR(sp, sq, s)  { GT2_CORE(sp, sq, s) }

__global__ __launch_bounds__(256, 1) void lstm_xg2(
    const unsigned short* __restrict__ xg,  // [B,T,1024] f16, bias folded
    const float* __restrict__ Wh,           // [H,4H]
    const float* __restrict__ Wout,         // [H,C]
    const float* __restrict__ bout,         // [C]
    float* __restrict__ out)                // [B,T,C]
{
    __shared__ alignas(16) unsigned short h_buf[2][2][Hh];  // [par][batch][u]
    __shared__ uint4 wl4[8][G4];       // tail pairs 96..127, 128 KB (shared)
    __shared__ float wout_t[Cc][Hh];
    __shared__ float bout_l[8];

    const int tid  = threadIdx.x;
    const int b0   = 2 * blockIdx.x;
    const int b1   = b0 + 1;
    const int colA = tid;          // gate i of unit tid
    const int colB = tid + 256;    // f
    const int colC = tid + 512;    // g
    const int colD = tid + 768;    // o

    // ---- prologue: 128 V-regs + 256 AGPRs + packed LDS tail ----
    REPV32(WLOADV4)
    REPA64(WLOADA4)

    #pragma unroll
    for (int jq = 0; jq < 8; ++jq) {   // tail: k rows 192+8jq .. 192+8jq+7
        const int kb = 192 + 8 * jq;
        wl4[jq][colA] = make_uint4(
            packh(Wh[(kb+0)*G4 + colA], Wh[(kb+1)*G4 + colA]),
            packh(Wh[(kb+2)*G4 + colA], Wh[(kb+3)*G4 + colA]),
            packh(Wh[(kb+4)*G4 + colA], Wh[(kb+5)*G4 + colA]),
            packh(Wh[(kb+6)*G4 + colA], Wh[(kb+7)*G4 + colA]));
        wl4[jq][colB] = make_uint4(
            packh(Wh[(kb+0)*G4 + colB], Wh[(kb+1)*G4 + colB]),
            packh(Wh[(kb+2)*G4 + colB], Wh[(kb+3)*G4 + colB]),
            packh(Wh[(kb+4)*G4 + colB], Wh[(kb+5)*G4 + colB]),
            packh(Wh[(kb+6)*G4 + colB], Wh[(kb+7)*G4 + colB]));
        wl4[jq][colC] = make_uint4(
            packh(Wh[(kb+0)*G4 + colC], Wh[(kb+1)*G4 + colC]),
            packh(Wh[(kb+2)*G4 + colC], Wh[(kb+3)*G4 + colC]),
            packh(Wh[(kb+4)*G4 + colC], Wh[(kb+5)*G4 + colC]),
            packh(Wh[(kb+6)*G4 + colC], Wh[(kb+7)*G4 + colC]));
        wl4[jq][colD] = make_uint4(
            packh(Wh[(kb+0)*G4 + colD], Wh[(kb+1)*G4 + colD]),
            packh(Wh[(kb+2)*G4 + colD], Wh[(kb+3)*G4 + colD]),
            packh(Wh[(kb+4)*G4 + colD], Wh[(kb+5)*G4 + colD]),
            packh(Wh[(kb+6)*G4 + colD], Wh[(kb+7)*G4 + colD]));
    }
    h_buf[0][0][tid] = 0;
    h_buf[0][1][tid] = 0;
    for (int i = tid; i < Cc * Hh; i += 256) wout_t[i % Cc][i / Cc] = Wout[i];
    if (tid < Cc) bout_l[tid] = bout[tid];

    const unsigned short* xgB0 = xg + (long)b0 * Tt * G4;
    const unsigned short* xgB1 = xg + (long)b1 * Tt * G4;
    unsigned short xA0 = xgB0[colA], xB0 = xgB0[colB], xC0 = xgB0[colC], xD0 = xgB0[colD];
    unsigned short xA1 = xgB1[colA], xB1 = xgB1[colB], xC1 = xgB1[colC], xD1 = xgB1[colD];
    float c0_state = 0.0f, c1_state = 0.0f;
    int par = 0;
    __syncthreads();

    // ---- time loop (one barrier/step; two interleaved batch streams) ----
    for (int t = 0; t < Tt; ++t) {
        unsigned short nA0 = 0, nB0 = 0, nC0 = 0, nD0 = 0;
        unsigned short nA1 = 0, nB1 = 0, nC1 = 0, nD1 = 0;
        if (t + 1 < Tt) {
            const unsigned short* x0 = xgB0 + (long)(t + 1) * G4;
            const unsigned short* x1 = xgB1 + (long)(t + 1) * G4;
            nA0 = x0[colA]; nB0 = x0[colB]; nC0 = x0[colC]; nD0 = x0[colD];
            nA1 = x1[colA]; nB1 = x1[colB]; nC1 = x1[colC]; nD1 = x1[colD];
        }

        const float4* hv0 = (const float4*)h_buf[par][0];  // batch0 h(t-1)
        const float4* hv1 = (const float4*)h_buf[par][1];  // batch1 h(t-1)
        float aA0 = 0.f, aB0 = 0.f, aC0 = 0.f, aD0 = 0.f;
        float aA1 = 0.f, aB1 = 0.f, aC1 = 0.f, aD1 = 0.f;

        // qbank temps (single bank) + tail dbuf
        float qA_0, qB_0, qC_0, qD_0, qA_1, qB_1, qC_1, qD_1;
        float qA_2, qB_2, qC_2, qD_2, qA_3, qB_3, qC_3, qD_3;
        uint4 twA0, twB0, twC0, twD0, twA1, twB1, twC1, twD1;

        // 2 rotating h slots per batch, primed 2 groups deep
        float4 sp0 = hv0[0], sp1 = hv0[1];
        float4 sq0 = hv1[0], sq1 = hv1[1];

        // V groups: pairs 0..31 (h groups 0..7), rotation loads 2..9
        GV2(sp0, sq0, 2,  0, 1, 2, 3)   GV2(sp1, sq1, 3,  4, 5, 6, 7)
        GV2(sp0, sq0, 4,  8, 9,10,11)   GV2(sp1, sq1, 5, 12,13,14,15)
        GV2(sp0, sq0, 6, 16,17,18,19)   GV2(sp1, sq1, 7, 20,21,22,23)
        GV2(sp0, sq0, 8, 24,25,26,27)   GV2(sp1, sq1, 9, 28,29,30,31)

        // A groups: pairs 32..95 (h groups 8..23), rotation loads 10..25
        AREADG1(32,33,34,35)  ADOTG2(sp0, sq0, 10)
        AREADG1(36,37,38,39)  ADOTG2(sp1, sq1, 11)
        AREADG1(40,41,42,43)  ADOTG2(sp0, sq0, 12)
        AREADG1(44,45,46,47)  ADOTG2(sp1, sq1, 13)
        AREADG1(48,49,50,51)  ADOTG2(sp0, sq0, 14)
        AREADG1(52,53,54,55)  ADOTG2(sp1, sq1, 15)
        AREADG1(56,57,58,59)  ADOTG2(sp0, sq0, 16)
        AREADG1(60,61,62,63)  ADOTG2(sp1, sq1, 17)
        AREADG1(64,65,66,67)  ADOTG2(sp0, sq0, 18)
        AREADG1(68,69,70,71)  ADOTG2(sp1, sq1, 19)
        AREADG1(72,73,74,75)  ADOTG2(sp0, sq0, 20)
        AREADG1(76,77,78,79)  ADOTG2(sp1, sq1, 21)
        TWL(0, 0)
        AREADG1(80,81,82,83)  ADOTG2(sp0, sq0, 22)
        TWL(1, 1)
        AREADG1(84,85,86,87)  ADOTG2(sp1, sq1, 23)
        AREADG1(88,89,90,91)  ADOTG2(sp0, sq0, 24)
        AREADG1(92,93,94,95)  ADOTG2(sp1, sq1, 25)

        // tail: pairs 96..127 (h groups 24..31), weights double-buffered
        GT2(sp0, sq0, 0, 26)  TWL(0, 2)
        GT2(sp1, sq1, 1, 27)  TWL(1, 3)
        GT2(sp0, sq0, 0, 28)  TWL(0, 4)
        GT2(sp1, sq1, 1, 29)  TWL(1, 5)
        GT2(sp0, sq0, 0, 30)  TWL(0, 6)
        GT2(sp1, sq1, 1, 31)  TWL(1, 7)
        GT2_NR(sp0, sq0, 0)
        GT2_NR(sp1, sq1, 1)

        // activations + state, both batches
        float ig0 = sigm(h2f(xA0) + aA0);
        float fg0 = sigm(h2f(xB0) + aB0);
        float gg0 = tanh_fast(h2f(xC0) + aC0);
        float og0 = sigm(h2f(xD0) + aD0);
        c0_state = fg0 * c0_state + ig0 * gg0;
        float hval0 = og0 * tanh_fast(c0_state);

        float ig1 = sigm(h2f(xA1) + aA1);
        float fg1 = sigm(h2f(xB1) + aB1);
        float gg1 = tanh_fast(h2f(xC1) + aC1);
        float og1 = sigm(h2f(xD1) + aD1);
        c1_state = fg1 * c1_state + ig1 * gg1;
        float hval1 = og1 * tanh_fast(c1_state);

        h_buf[par ^ 1][0][tid] = f2h(hval0);
        h_buf[par ^ 1][1][tid] = f2h(hval1);
        __syncthreads();   // h(t) visible; h(t-1) reads all complete

        // fused output projection: wave w -> class w for BOTH batches;
        // waves 0,1 also batch0 classes 4,5; waves 2,3 also batch1 classes 4,5
        const unsigned short* hn0 = h_buf[par ^ 1][0];
        const unsigned short* hn1 = h_buf[par ^ 1][1];
        const int w = tid >> 6, l = tid & 63;
        {
            float p = 0.0f;
            #pragma unroll
            for (int j = 0; j < 4; ++j)
                p += h2f(hn0[l + 64 * j]) * wout_t[w][l + 64 * j];
            #pragma unroll
            for (int off = 32; off > 0; off >>= 1) p += __shfl_down(p, off);
            if (l == 0) out[((long)b0 * Tt + t) * Cc + w] = p + bout_l[w];
        }
        {
            float p = 0.0f;
            #pragma unroll
            for (int j = 0; j < 4; ++j)
                p += h2f(hn1[l + 64 * j]) * wout_t[w][l + 64 * j];
            #pragma unroll
            for (int off = 32; off > 0; off >>= 1) p += __shfl_down(p, off);
            if (l == 0) out[((long)b1 * Tt + t) * Cc + w] = p + bout_l[w];
        }
        {
            const int c2 = (w < 2) ? (4 + w) : (4 + (w - 2));
            const unsigned short* hx = (w < 2) ? hn0 : hn1;
            const long bb = (w < 2) ? b0 : b1;
            float p = 0.0f;
            #pragma unroll
            for (int j = 0; j < 4; ++j)
                p += h2f(hx[l + 64 * j]) * wout_t[c2][l + 64 * j];
            #pragma unroll
            for (int off = 32; off > 0; off >>= 1) p += __shfl_down(p, off);
            if (l == 0) out[(bb * Tt + t) * Cc + c2] = p + bout_l[c2];
        }

        xA0 = nA0; xB0 = nB0; xC0 = nC0; xD0 = nD0;
        xA1 = nA1; xB1 = nB1; xC1 = nC1; xD1 = nD1;
        par ^= 1;
    }
}

// ---------------- fallback: R2 single-block kernel (no ws needed) ----------
__global__ __launch_bounds__(1024) void lstm_fused(
    const float* __restrict__ x, const float* __restrict__ Wx,
    const float* __restrict__ Wh, const float* __restrict__ bias,
    const float* __restrict__ Wout, const float* __restrict__ bout,
    float* __restrict__ out)
{
    __shared__ float h_lds[Hh];
    __shared__ float gates_lds[G4];
    __shared__ float x_lds[2][Dd];
    __shared__ float wout_t[Cc][Hh];
    __shared__ float bout_l[Cc];
    const int tid = threadIdx.x;
    const int b   = blockIdx.x;
    float wx[Dd];
    #pragma unroll
    for (int d = 0; d < Dd; ++d) wx[d] = Wx[d * G4 + tid];
    const float bj = bias[tid];
    if (tid < Hh) h_lds[tid] = 0.0f;
    for (int i = tid; i < Cc * Hh; i += 1024) wout_t[i % Cc][i / Cc] = Wout[i];
    if (tid < Cc) bout_l[tid] = bout[tid];
    const float* xB = x + (long)b * Tt * Dd;
    if (tid < Dd) x_lds[0][tid] = xB[tid];
    float c_state = 0.0f;
    __syncthreads();
    const float* WhB = Wh + tid;
    for (int t = 0; t < Tt; ++t) {
        float gg = bj;
        const float* xr = x_lds[t & 1];
        #pragma unroll
        for (int d = 0; d < Dd; ++d) gg += xr[d] * wx[d];
        #pragma unroll 8
        for (int k = 0; k < Hh; ++k) gg += h_lds[k] * WhB[k * G4];
        float a;
        if (tid < 2 * Hh)      a = 1.0f / (1.0f + expf(-gg));
        else if (tid < 3 * Hh) a = tanhf(gg);
        else                   a = 1.0f / (1.0f + expf(-gg));
        gates_lds[tid] = a;
        __syncthreads();
        if (tid < Hh) {
            float iv = gates_lds[tid], fv = gates_lds[tid + Hh];
            float gv = gates_lds[tid + 2 * Hh], ov = gates_lds[tid + 3 * Hh];
            c_state = fv * c_state + iv * gv;
            h_lds[tid] = ov * tanhf(c_state);
        } else if (tid >= 384 && tid < 448) {
            int tn = t + 1;
            if (tn < Tt) x_lds[tn & 1][tid - 384] = xB[(long)tn * Dd + (tid - 384)];
        }
        __syncthreads();
        const int w = tid >> 6, l = tid & 63;
        if (w < Cc) {
            float p = 0.0f;
            #pragma unroll
            for (int qq = 0; qq < 4; ++qq) p += h_lds[l + 64 * qq] * wout_t[w][l + 64 * qq];
            #pragma unroll
            for (int off = 32; off > 0; off >>= 1) p += __shfl_down(p, off);
            if (l == 0) out[((long)b * Tt + t) * Cc + w] = p + bout_l[w];
        }
    }
}

extern "C" void kernel_launch(void* const* d_in, const int* in_sizes, int n_in,
                              void* d_out, int out_size, void* d_ws, size_t ws_size,
                              hipStream_t stream) {
    const float* x    = (const float*)d_in[0];
    const float* Wx   = (const float*)d_in[1];
    const float* Wh   = (const float*)d_in[2];
    const float* bvec = (const float*)d_in[3];
    const float* Wout = (const float*)d_in[4];
    const float* bout = (const float*)d_in[5];
    float* outp = (float*)d_out;

    if (ws_size >= XG_BYTES) {
        unsigned short* xgws = (unsigned short*)d_ws;
        xg_gemm<<<dim3(BT / 32, 4), dim3(256), 0, stream>>>(x, Wx, bvec, xgws);
        lstm_xg2<<<dim3(64), dim3(256), 0, stream>>>(xgws, Wh, Wout, bout, outp);
    } else {
        lstm_fused<<<dim3(128), dim3(1024), 0, stream>>>(x, Wx, Wh, bvec, Wout, bout, outp);
    }
}

// Round 17
// 2513.088 us; speedup vs baseline: 1.8403x; 1.8403x over previous
//
#include <hip/hip_runtime.h>
#include <math.h>

// LSTM B=128,T=1024,D=64,H=256,C=6 — R17: R15 base, projection evicted from
// the loop + tail-weight triple-buffer.
//
// R16 lesson: wall time = 1024 x single-step latency (all blocks concurrent);
// batches/block only raises step latency. Optimize tau on one CU.
// R15 tau=2.87us: VALU 1760cy, LDS pipe ~2200-3500cy (tail b128 + h bcast +
// PROJECTION: wout reads + 12-24 ds_bpermute shuffles + 180cy reduce chain).
//  * h(t) stored to the consumed xg row t (u16, fire-and-forget) -> projection
//    runs as a tiny post-pass GEMM on all CUs (out_proj, ~20us)
//  * tail weights triple-buffered: 3-group (~190cy) lead >= LDS latency
//    (R15's 2-buffer lead was 1 group = 64cy -> ~350cy/step exposed)
//  * xg_gemm: float4 LDS reads (R16 version)
// Numerics identical (f16 weights/h/xg, fp32 accum): absmax 3.9e-3.

#define Tt 1024
#define Dd 64
#define Hh 256
#define G4 1024
#define Cc 6
#define BT (128 * 1024)
#define XG_BYTES ((size_t)BT * G4 * 2)   // 256 MB f16

typedef _Float16 f16x2 __attribute__((ext_vector_type(2)));

__device__ __forceinline__ float dot2(f16x2 a, f16x2 b, float c) {
#if __has_builtin(__builtin_amdgcn_fdot2)
    return __builtin_amdgcn_fdot2(a, b, c, false);
#else
    return c + (float)a.x * (float)b.x + (float)a.y * (float)b.y;
#endif
}
__device__ __forceinline__ float sigm(float p) { return 1.0f / (1.0f + __expf(-p)); }
__device__ __forceinline__ float tanh_fast(float p) {
    return 1.0f - 2.0f / (__expf(2.0f * p) + 1.0f);
}
__device__ __forceinline__ unsigned short f2h(float v) {
    _Float16 h = (_Float16)v;
    return __builtin_bit_cast(unsigned short, h);
}
__device__ __forceinline__ float h2f(unsigned short u) {
    return (float)__builtin_bit_cast(_Float16, u);
}
__device__ __forceinline__ f16x2 bcf(float v) { return __builtin_bit_cast(f16x2, v); }
__device__ __forceinline__ f16x2 bcu(unsigned int v) { return __builtin_bit_cast(f16x2, v); }
__device__ __forceinline__ unsigned int packh(float a, float b) {
    return (unsigned int)f2h(a) | ((unsigned int)f2h(b) << 16);
}

// ---------------- stage 1: xg = x @ Wx + bias, f16 -------------------------
__global__ __launch_bounds__(256) void xg_gemm(
    const float* __restrict__ x, const float* __restrict__ Wx,
    const float* __restrict__ bias, unsigned short* __restrict__ xg)
{
    __shared__ float xs[32][65];
    __shared__ float wsl[64][256];

    const int tid = threadIdx.x;
    const long r0 = (long)blockIdx.x * 32;
    const int  c0 = blockIdx.y * 256;

    {
        const float4* src = (const float4*)(x + r0 * Dd);
        float4 v0 = src[tid], v1 = src[tid + 256];
        int e = tid * 4;
        xs[e >> 6][e & 63] = v0.x; xs[e >> 6][(e & 63) + 1] = v0.y;
        xs[e >> 6][(e & 63) + 2] = v0.z; xs[e >> 6][(e & 63) + 3] = v0.w;
        e += 1024;
        xs[e >> 6][e & 63] = v1.x; xs[e >> 6][(e & 63) + 1] = v1.y;
        xs[e >> 6][(e & 63) + 2] = v1.z; xs[e >> 6][(e & 63) + 3] = v1.w;
    }
    for (int i = tid; i < 64 * 64; i += 256) {
        int d = i >> 6, cq = i & 63;
        *(float4*)&wsl[d][cq * 4] = *(const float4*)(Wx + (long)d * G4 + c0 + cq * 4);
    }
    __syncthreads();

    const int r = tid & 31, cg = tid >> 5;
    float acc[32];
    #pragma unroll
    for (int c = 0; c < 32; ++c) acc[c] = bias[c0 + cg * 32 + c];
    for (int k = 0; k < 64; ++k) {
        float xv = xs[r][k];
        const float4* wr = (const float4*)&wsl[k][cg * 32];
        #pragma unroll
        for (int c4 = 0; c4 < 8; ++c4) {
            float4 wv = wr[c4];
            acc[4*c4+0] += xv * wv.x; acc[4*c4+1] += xv * wv.y;
            acc[4*c4+2] += xv * wv.z; acc[4*c4+3] += xv * wv.w;
        }
    }
    unsigned int ow[16];
    #pragma unroll
    for (int c2 = 0; c2 < 16; ++c2)
        ow[c2] = packh(acc[2 * c2], acc[2 * c2 + 1]);
    uint4* dst = (uint4*)(xg + (r0 + r) * G4 + c0 + cg * 32);
    dst[0] = make_uint4(ow[0], ow[1], ow[2], ow[3]);
    dst[1] = make_uint4(ow[4], ow[5], ow[6], ow[7]);
    dst[2] = make_uint4(ow[8], ow[9], ow[10], ow[11]);
    dst[3] = make_uint4(ow[12], ow[13], ow[14], ow[15]);
}

// ---------------- stage 3: output projection (post-pass) -------------------
__global__ __launch_bounds__(256) void out_proj(
    const unsigned short* __restrict__ hs,  // [B,T,1024]; h(t) in first 256
    const float* __restrict__ Wout,         // [256,6]
    const float* __restrict__ bout,         // [6]
    float* __restrict__ out)                // [B,T,6]
{
    __shared__ float wt[Cc][Hh];
    const int tid = threadIdx.x;
    for (int i = tid; i < Cc * Hh; i += 256) wt[i % Cc][i / Cc] = Wout[i];
    __syncthreads();

    const int b = blockIdx.x;
    const int t = blockIdx.y * 256 + tid;
    const uint4* h4 = (const uint4*)(hs + ((long)b * Tt + t) * G4);
    float a0 = bout[0], a1 = bout[1], a2 = bout[2];
    float a3 = bout[3], a4 = bout[4], a5 = bout[5];
    #pragma unroll
    for (int j = 0; j < 32; ++j) {          // 8 h values per uint4
        uint4 hv = h4[j];
        const unsigned int hw[4] = { hv.x, hv.y, hv.z, hv.w };
        #pragma unroll
        for (int q = 0; q < 4; ++q) {
            float hlo = h2f((unsigned short)(hw[q] & 0xffff));
            float hhi = h2f((unsigned short)(hw[q] >> 16));
            int m = j * 8 + 2 * q;
            a0 += hlo * wt[0][m] + hhi * wt[0][m + 1];
            a1 += hlo * wt[1][m] + hhi * wt[1][m + 1];
            a2 += hlo * wt[2][m] + hhi * wt[2][m + 1];
            a3 += hlo * wt[3][m] + hhi * wt[3][m + 1];
            a4 += hlo * wt[4][m] + hhi * wt[4][m + 1];
            a5 += hlo * wt[5][m] + hhi * wt[5][m + 1];
        }
    }
    float* orow = out + ((long)b * Tt + t) * Cc;
    orow[0] = a0; orow[1] = a1; orow[2] = a2;
    orow[3] = a3; orow[4] = a4; orow[5] = a5;
}

// ---------------- stage 2: recurrence -------------------------------------
// pair i covers k = 2i,2i+1; cols A,B,C,D = gates i,f,g,o of unit tid.

#define WLOADV4(i) \
  const f16x2 wA_##i = f16x2{(_Float16)Wh[(2*(i))*G4 + colA], (_Float16)Wh[(2*(i)+1)*G4 + colA]}; \
  const f16x2 wB_##i = f16x2{(_Float16)Wh[(2*(i))*G4 + colB], (_Float16)Wh[(2*(i)+1)*G4 + colB]}; \
  const f16x2 wC_##i = f16x2{(_Float16)Wh[(2*(i))*G4 + colC], (_Float16)Wh[(2*(i)+1)*G4 + colC]}; \
  const f16x2 wD_##i = f16x2{(_Float16)Wh[(2*(i))*G4 + colD], (_Float16)Wh[(2*(i)+1)*G4 + colD]};

#define AW1(dst, cix, i) { \
    f16x2 t_ = f16x2{(_Float16)Wh[(2*(i))*G4 + (cix)], (_Float16)Wh[(2*(i)+1)*G4 + (cix)]}; \
    asm volatile("v_accvgpr_write_b32 %0, %1" : "=a"(dst) : "v"(__builtin_bit_cast(float, t_))); }

#define WLOADA4(i) \
  float awA_##i, awB_##i, awC_##i, awD_##i; \
  AW1(awA_##i, colA, i) AW1(awB_##i, colB, i) \
  AW1(awC_##i, colC, i) AW1(awD_##i, colD, i)

#define REPV32(M) \
  M(0) M(1) M(2) M(3) M(4) M(5) M(6) M(7) \
  M(8) M(9) M(10) M(11) M(12) M(13) M(14) M(15) \
  M(16) M(17) M(18) M(19) M(20) M(21) M(22) M(23) \
  M(24) M(25) M(26) M(27) M(28) M(29) M(30) M(31)

#define REPA64(M) \
  M(32) M(33) M(34) M(35) M(36) M(37) M(38) M(39) \
  M(40) M(41) M(42) M(43) M(44) M(45) M(46) M(47) \
  M(48) M(49) M(50) M(51) M(52) M(53) M(54) M(55) \
  M(56) M(57) M(58) M(59) M(60) M(61) M(62) M(63) \
  M(64) M(65) M(66) M(67) M(68) M(69) M(70) M(71) \
  M(72) M(73) M(74) M(75) M(76) M(77) M(78) M(79) \
  M(80) M(81) M(82) M(83) M(84) M(85) M(86) M(87) \
  M(88) M(89) M(90) M(91) M(92) M(93) M(94) M(95)

#define DOTPV(i, hh) { f16x2 h_ = (hh); \
    aA = dot2(h_, wA_##i, aA); aB = dot2(h_, wB_##i, aB); \
    aC = dot2(h_, wC_##i, aC); aD = dot2(h_, wD_##i, aD); }

#define GV(s, n, i0,i1,i2,i3) { \
    DOTPV(i0, bcf(s.x)) DOTPV(i1, bcf(s.y)) \
    DOTPV(i2, bcf(s.z)) DOTPV(i3, bcf(s.w)) \
    s = hvf4[n]; }

#define ARD(dst, src) \
    asm volatile("v_accvgpr_read_b32 %0, %1" : "=v"(dst) : "a"(src));

#define AREADG(bk, i0,i1,i2,i3) \
    ARD(qA##bk##_0, awA_##i0) ARD(qB##bk##_0, awB_##i0) ARD(qC##bk##_0, awC_##i0) ARD(qD##bk##_0, awD_##i0) \
    ARD(qA##bk##_1, awA_##i1) ARD(qB##bk##_1, awB_##i1) ARD(qC##bk##_1, awC_##i1) ARD(qD##bk##_1, awD_##i1) \
    ARD(qA##bk##_2, awA_##i2) ARD(qB##bk##_2, awB_##i2) ARD(qC##bk##_2, awC_##i2) ARD(qD##bk##_2, awD_##i2) \
    ARD(qA##bk##_3, awA_##i3) ARD(qB##bk##_3, awB_##i3) ARD(qC##bk##_3, awC_##i3) ARD(qD##bk##_3, awD_##i3)

#define ADOTSG(bk, hs) { \
    f16x2 h0 = bcf(hs.x), h1 = bcf(hs.y), h2 = bcf(hs.z), h3 = bcf(hs.w); \
    aA = dot2(h0, bcf(qA##bk##_0), aA); aB = dot2(h0, bcf(qB##bk##_0), aB); \
    aC = dot2(h0, bcf(qC##bk##_0), aC); aD = dot2(h0, bcf(qD##bk##_0), aD); \
    aA = dot2(h1, bcf(qA##bk##_1), aA); aB = dot2(h1, bcf(qB##bk##_1), aB); \
    aC = dot2(h1, bcf(qC##bk##_1), aC); aD = dot2(h1, bcf(qD##bk##_1), aD); \
    aA = dot2(h2, bcf(qA##bk##_2), aA); aB = dot2(h2, bcf(qB##bk##_2), aB); \
    aC = dot2(h2, bcf(qC##bk##_2), aC); aD = dot2(h2, bcf(qD##bk##_2), aD); \
    aA = dot2(h3, bcf(qA##bk##_3), aA); aB = dot2(h3, bcf(qB##bk##_3), aB); \
    aC = dot2(h3, bcf(qC##bk##_3), aC); aD = dot2(h3, bcf(qD##bk##_3), aD); }

#define TWL(s, jq) { twA##s = wl4[jq][colA]; twB##s = wl4[jq][colB]; \
                     twC##s = wl4[jq][colC]; twD##s = wl4[jq][colD]; }

#define GT(hs, s) { \
    f16x2 h0 = bcf(hs.x), h1 = bcf(hs.y), h2 = bcf(hs.z), h3 = bcf(hs.w); \
    aA = dot2(h0, bcu(twA##s.x), aA); aA = dot2(h1, bcu(twA##s.y), aA); \
    aA = dot2(h2, bcu(twA##s.z), aA); aA = dot2(h3, bcu(twA##s.w), aA); \
    aB = dot2(h0, bcu(twB##s.x), aB); aB = dot2(h1, bcu(twB##s.y), aB); \
    aB = dot2(h2, bcu(twB##s.z), aB); aB = dot2(h3, bcu(twB##s.w), aB); \
    aC = dot2(h0, bcu(twC##s.x), aC); aC = dot2(h1, bcu(twC##s.y), aC); \
    aC = dot2(h2, bcu(twC##s.z), aC); aC = dot2(h3, bcu(twC##s.w), aC); \
    aD = dot2(h0, bcu(twD##s.x), aD); aD = dot2(h1, bcu(twD##s.y), aD); \
    aD = dot2(h2, bcu(twD##s.z), aD); aD = dot2(h3, bcu(twD##s.w), aD); }

__global__ __launch_bounds__(256, 1) void lstm_xg(
    unsigned short* __restrict__ xg,        // [B,T,1024] f16 in+h out
    const float* __restrict__ Wh)           // [H,4H]
{
    __shared__ alignas(16) unsigned short h_buf[2][Hh];  // double-buffered h
    __shared__ uint4 wl4[8][G4];       // tail pairs 96..127, 128 KB

    const int tid  = threadIdx.x;
    const int b    = blockIdx.x;
    const int colA = tid;          // gate i of unit tid
    const int colB = tid + 256;    // f
    const int colC = tid + 512;    // g
    const int colD = tid + 768;    // o

    // ---- prologue: 128 V-regs + 256 AGPRs + packed LDS tail ----
    REPV32(WLOADV4)
    REPA64(WLOADA4)

    #pragma unroll
    for (int jq = 0; jq < 8; ++jq) {   // tail: k rows 192+8jq .. 192+8jq+7
        const int kb = 192 + 8 * jq;
        wl4[jq][colA] = make_uint4(
            packh(Wh[(kb+0)*G4 + colA], Wh[(kb+1)*G4 + colA]),
            packh(Wh[(kb+2)*G4 + colA], Wh[(kb+3)*G4 + colA]),
            packh(Wh[(kb+4)*G4 + colA], Wh[(kb+5)*G4 + colA]),
            packh(Wh[(kb+6)*G4 + colA], Wh[(kb+7)*G4 + colA]));
        wl4[jq][colB] = make_uint4(
            packh(Wh[(kb+0)*G4 + colB], Wh[(kb+1)*G4 + colB]),
            packh(Wh[(kb+2)*G4 + colB], Wh[(kb+3)*G4 + colB]),
            packh(Wh[(kb+4)*G4 + colB], Wh[(kb+5)*G4 + colB]),
            packh(Wh[(kb+6)*G4 + colB], Wh[(kb+7)*G4 + colB]));
        wl4[jq][colC] = make_uint4(
            packh(Wh[(kb+0)*G4 + colC], Wh[(kb+1)*G4 + colC]),
            packh(Wh[(kb+2)*G4 + colC], Wh[(kb+3)*G4 + colC]),
            packh(Wh[(kb+4)*G4 + colC], Wh[(kb+5)*G4 + colC]),
            packh(Wh[(kb+6)*G4 + colC], Wh[(kb+7)*G4 + colC]));
        wl4[jq][colD] = make_uint4(
            packh(Wh[(kb+0)*G4 + colD], Wh[(kb+1)*G4 + colD]),
            packh(Wh[(kb+2)*G4 + colD], Wh[(kb+3)*G4 + colD]),
            packh(Wh[(kb+4)*G4 + colD], Wh[(kb+5)*G4 + colD]),
            packh(Wh[(kb+6)*G4 + colD], Wh[(kb+7)*G4 + colD]));
    }
    h_buf[0][tid] = 0;

    unsigned short* xgB = xg + (long)b * Tt * G4;
    unsigned short xgA = xgB[colA], xgBv = xgB[colB];
    unsigned short xgC = xgB[colC], xgD = xgB[colD];
    float c_state = 0.0f;
    int par = 0;
    __syncthreads();

    // ---- time loop: one barrier/step, no projection ----
    for (int t = 0; t < Tt; ++t) {
        unsigned short nA = 0, nB = 0, nC = 0, nD = 0;
        if (t + 1 < Tt) {
            const unsigned short* xn = xgB + (long)(t + 1) * G4;
            nA = xn[colA]; nB = xn[colB]; nC = xn[colC]; nD = xn[colD];
        }

        const float4* hvf4 = (const float4*)h_buf[par];  // h(t-1), broadcast
        float aA = 0.f, aB = 0.f, aC = 0.f, aD = 0.f;

        float qA0_0, qB0_0, qC0_0, qD0_0, qA0_1, qB0_1, qC0_1, qD0_1;
        float qA0_2, qB0_2, qC0_2, qD0_2, qA0_3, qB0_3, qC0_3, qD0_3;
        float qA1_0, qB1_0, qC1_0, qD1_0, qA1_1, qB1_1, qC1_1, qD1_1;
        float qA1_2, qB1_2, qC1_2, qD1_2, qA1_3, qB1_3, qC1_3, qD1_3;
        uint4 twA0, twB0, twC0, twD0, twA1, twB1, twC1, twD1;
        uint4 twA2, twB2, twC2, twD2;

        // 4 rotating h slots, primed 4 groups deep
        float4 hs0 = hvf4[0], hs1 = hvf4[1], hs2 = hvf4[2], hs3 = hvf4[3];

        // V groups: pairs 0..31 (h groups 0..7)
        GV(hs0, 4,   0, 1, 2, 3)   GV(hs1, 5,   4, 5, 6, 7)
        GV(hs2, 6,   8, 9,10,11)   GV(hs3, 7,  12,13,14,15)
        GV(hs0, 8,  16,17,18,19)   GV(hs1, 9,  20,21,22,23)
        GV(hs2, 10, 24,25,26,27)   GV(hs3, 11, 28,29,30,31)

        // A bank pipeline: reads for group k+1 precede dots of group k
        AREADG(0, 32,33,34,35)
        AREADG(1, 36,37,38,39)  ADOTSG(0, hs0)  hs0 = hvf4[12];
        AREADG(0, 40,41,42,43)  ADOTSG(1, hs1)  hs1 = hvf4[13];
        AREADG(1, 44,45,46,47)  ADOTSG(0, hs2)  hs2 = hvf4[14];
        AREADG(0, 48,49,50,51)  ADOTSG(1, hs3)  hs3 = hvf4[15];
        AREADG(1, 52,53,54,55)  ADOTSG(0, hs0)  hs0 = hvf4[16];
        AREADG(0, 56,57,58,59)  ADOTSG(1, hs1)  hs1 = hvf4[17];
        AREADG(1, 60,61,62,63)  ADOTSG(0, hs2)  hs2 = hvf4[18];
        AREADG(0, 64,65,66,67)  ADOTSG(1, hs3)  hs3 = hvf4[19];
        AREADG(1, 68,69,70,71)  ADOTSG(0, hs0)  hs0 = hvf4[20];
        AREADG(0, 72,73,74,75)  ADOTSG(1, hs1)  hs1 = hvf4[21];
        TWL(0, 0)
        AREADG(1, 76,77,78,79)  ADOTSG(0, hs2)  hs2 = hvf4[22];
        AREADG(0, 80,81,82,83)  ADOTSG(1, hs3)  hs3 = hvf4[23];
        TWL(1, 1)
        AREADG(1, 84,85,86,87)  ADOTSG(0, hs0)  hs0 = hvf4[24];
        AREADG(0, 88,89,90,91)  ADOTSG(1, hs1)  hs1 = hvf4[25];
        TWL(2, 2)
        AREADG(1, 92,93,94,95)  ADOTSG(0, hs2)  hs2 = hvf4[26];
                                ADOTSG(1, hs3)  hs3 = hvf4[27];

        // tail: pairs 96..127 (h groups 24..31), 3-buffer rotation
        GT(hs0, 0)  TWL(0, 3)  hs0 = hvf4[28];
        GT(hs1, 1)  TWL(1, 4)  hs1 = hvf4[29];
        GT(hs2, 2)  TWL(2, 5)  hs2 = hvf4[30];
        GT(hs3, 0)  TWL(0, 6)  hs3 = hvf4[31];
        GT(hs0, 1)  TWL(1, 7)
        GT(hs1, 2)
        GT(hs2, 0)
        GT(hs3, 1)

        float ig = sigm(h2f(xgA) + aA);
        float fg = sigm(h2f(xgBv) + aB);
        float gg = tanh_fast(h2f(xgC) + aC);
        float og = sigm(h2f(xgD) + aD);
        c_state = fg * c_state + ig * gg;
        float hval = og * tanh_fast(c_state);

        unsigned short hb = f2h(hval);
        h_buf[par ^ 1][tid] = hb;         // LDS for next step
        xgB[(long)t * G4 + tid] = hb;     // global (row t already consumed)
        __syncthreads();                   // h(t) visible

        xgA = nA; xgBv = nB; xgC = nC; xgD = nD;
        par ^= 1;
    }
}

// ---------------- fallback: R2 single-block kernel (no ws needed) ----------
__global__ __launch_bounds__(1024) void lstm_fused(
    const float* __restrict__ x, const float* __restrict__ Wx,
    const float* __restrict__ Wh, const float* __restrict__ bias,
    const float* __restrict__ Wout, const float* __restrict__ bout,
    float* __restrict__ out)
{
    __shared__ float h_lds[Hh];
    __shared__ float gates_lds[G4];
    __shared__ float x_lds[2][Dd];
    __shared__ float wout_t[Cc][Hh];
    __shared__ float bout_l[Cc];
    const int tid = threadIdx.x;
    const int b   = blockIdx.x;
    float wx[Dd];
    #pragma unroll
    for (int d = 0; d < Dd; ++d) wx[d] = Wx[d * G4 + tid];
    const float bj = bias[tid];
    if (tid < Hh) h_lds[tid] = 0.0f;
    for (int i = tid; i < Cc * Hh; i += 1024) wout_t[i % Cc][i / Cc] = Wout[i];
    if (tid < Cc) bout_l[tid] = bout[tid];
    const float* xB = x + (long)b * Tt * Dd;
    if (tid < Dd) x_lds[0][tid] = xB[tid];
    float c_state = 0.0f;
    __syncthreads();
    const float* WhB = Wh + tid;
    for (int t = 0; t < Tt; ++t) {
        float gg = bj;
        const float* xr = x_lds[t & 1];
        #pragma unroll
        for (int d = 0; d < Dd; ++d) gg += xr[d] * wx[d];
        #pragma unroll 8
        for (int k = 0; k < Hh; ++k) gg += h_lds[k] * WhB[k * G4];
        float a;
        if (tid < 2 * Hh)      a = 1.0f / (1.0f + expf(-gg));
        else if (tid < 3 * Hh) a = tanhf(gg);
        else                   a = 1.0f / (1.0f + expf(-gg));
        gates_lds[tid] = a;
        __syncthreads();
        if (tid < Hh) {
            float iv = gates_lds[tid], fv = gates_lds[tid + Hh];
            float gv = gates_lds[tid + 2 * Hh], ov = gates_lds[tid + 3 * Hh];
            c_state = fv * c_state + iv * gv;
            h_lds[tid] = ov * tanhf(c_state);
        } else if (tid >= 384 && tid < 448) {
            int tn = t + 1;
            if (tn < Tt) x_lds[tn & 1][tid - 384] = xB[(long)tn * Dd + (tid - 384)];
        }
        __syncthreads();
        const int w = tid >> 6, l = tid & 63;
        if (w < Cc) {
            float p = 0.0f;
            #pragma unroll
            for (int qq = 0; qq < 4; ++qq) p += h_lds[l + 64 * qq] * wout_t[w][l + 64 * qq];
            #pragma unroll
            for (int off = 32; off > 0; off >>= 1) p += __shfl_down(p, off);
            if (l == 0) out[((long)b * Tt + t) * Cc + w] = p + bout_l[w];
        }
    }
}

extern "C" void kernel_launch(void* const* d_in, const int* in_sizes, int n_in,
                              void* d_out, int out_size, void* d_ws, size_t ws_size,
                              hipStream_t stream) {
    const float* x    = (const float*)d_in[0];
    const float* Wx   = (const float*)d_in[1];
    const float* Wh   = (const float*)d_in[2];
    const float* bvec = (const float*)d_in[3];
    const float* Wout = (const float*)d_in[4];
    const float* bout = (const float*)d_in[5];
    float* outp = (float*)d_out;

    if (ws_size >= XG_BYTES) {
        unsigned short* xgws = (unsigned short*)d_ws;
        xg_gemm<<<dim3(BT / 32, 4), dim3(256), 0, stream>>>(x, Wx, bvec, xgws);
        lstm_xg<<<dim3(128), dim3(256), 0, stream>>>(xgws, Wh);
        out_proj<<<dim3(128, 4), dim3(256), 0, stream>>>(xgws, Wout, bout, outp);
    } else {
        lstm_fused<<<dim3(128), dim3(1024), 0, stream>>>(x, Wx, Wh, bvec, Wout, bout, outp);
    }
}

// Round 18
// 2506.431 us; speedup vs baseline: 1.8452x; 1.0027x over previous
//
#include <hip/hip_runtime.h>
#include <math.h>

// LSTM B=128,T=1024,D=64,H=256,C=6 — R17: R15 base, projection evicted from
// the loop + tail-weight triple-buffer.
//
// R16 lesson: wall time = 1024 x single-step latency (all blocks concurrent);
// batches/block only raises step latency. Optimize tau on one CU.
// R15 tau=2.87us: VALU 1760cy, LDS pipe ~2200-3500cy (tail b128 + h bcast +
// PROJECTION: wout reads + 12-24 ds_bpermute shuffles + 180cy reduce chain).
//  * h(t) stored to the consumed xg row t (u16, fire-and-forget) -> projection
//    runs as a tiny post-pass GEMM on all CUs (out_proj, ~20us)
//  * tail weights triple-buffered: 3-group (~190cy) lead >= LDS latency
//    (R15's 2-buffer lead was 1 group = 64cy -> ~350cy/step exposed)
//  * xg_gemm: float4 LDS reads (R16 version)
// Numerics identical (f16 weights/h/xg, fp32 accum): absmax 3.9e-3.

#define Tt 1024
#define Dd 64
#define Hh 256
#define G4 1024
#define Cc 6
#define BT (128 * 1024)
#define XG_BYTES ((size_t)BT * G4 * 2)   // 256 MB f16

typedef _Float16 f16x2 __attribute__((ext_vector_type(2)));

__device__ __forceinline__ float dot2(f16x2 a, f16x2 b, float c) {
#if __has_builtin(__builtin_amdgcn_fdot2)
    return __builtin_amdgcn_fdot2(a, b, c, false);
#else
    return c + (float)a.x * (float)b.x + (float)a.y * (float)b.y;
#endif
}
__device__ __forceinline__ float sigm(float p) { return 1.0f / (1.0f + __expf(-p)); }
__device__ __forceinline__ float tanh_fast(float p) {
    return 1.0f - 2.0f / (__expf(2.0f * p) + 1.0f);
}
__device__ __forceinline__ unsigned short f2h(float v) {
    _Float16 h = (_Float16)v;
    return __builtin_bit_cast(unsigned short, h);
}
__device__ __forceinline__ float h2f(unsigned short u) {
    return (float)__builtin_bit_cast(_Float16, u);
}
__device__ __forceinline__ f16x2 bcf(float v) { return __builtin_bit_cast(f16x2, v); }
__device__ __forceinline__ f16x2 bcu(unsigned int v) { return __builtin_bit_cast(f16x2, v); }
__device__ __forceinline__ unsigned int packh(float a, float b) {
    return (unsigned int)f2h(a) | ((unsigned int)f2h(b) << 16);
}

// ---------------- stage 1: xg = x @ Wx + bias, f16 -------------------------
__global__ __launch_bounds__(256) void xg_gemm(
    const float* __restrict__ x, const float* __restrict__ Wx,
    const float* __restrict__ bias, unsigned short* __restrict__ xg)
{
    __shared__ float xs[32][65];
    __shared__ float wsl[64][256];

    const int tid = threadIdx.x;
    const long r0 = (long)blockIdx.x * 32;
    const int  c0 = blockIdx.y * 256;

    {
        const float4* src = (const float4*)(x + r0 * Dd);
        float4 v0 = src[tid], v1 = src[tid + 256];
        int e = tid * 4;
        xs[e >> 6][e & 63] = v0.x; xs[e >> 6][(e & 63) + 1] = v0.y;
        xs[e >> 6][(e & 63) + 2] = v0.z; xs[e >> 6][(e & 63) + 3] = v0.w;
        e += 1024;
        xs[e >> 6][e & 63] = v1.x; xs[e >> 6][(e & 63) + 1] = v1.y;
        xs[e >> 6][(e & 63) + 2] = v1.z; xs[e >> 6][(e & 63) + 3] = v1.w;
    }
    for (int i = tid; i < 64 * 64; i += 256) {
        int d = i >> 6, cq = i & 63;
        *(float4*)&wsl[d][cq * 4] = *(const float4*)(Wx + (long)d * G4 + c0 + cq * 4);
    }
    __syncthreads();

    const int r = tid & 31, cg = tid >> 5;
    float acc[32];
    #pragma unroll
    for (int c = 0; c < 32; ++c) acc[c] = bias[c0 + cg * 32 + c];
    for (int k = 0; k < 64; ++k) {
        float xv = xs[r][k];
        const float4* wr = (const float4*)&wsl[k][cg * 32];
        #pragma unroll
        for (int c4 = 0; c4 < 8; ++c4) {
            float4 wv = wr[c4];
            acc[4*c4+0] += xv * wv.x; acc[4*c4+1] += xv * wv.y;
            acc[4*c4+2] += xv * wv.z; acc[4*c4+3] += xv * wv.w;
        }
    }
    unsigned int ow[16];
    #pragma unroll
    for (int c2 = 0; c2 < 16; ++c2)
        ow[c2] = packh(acc[2 * c2], acc[2 * c2 + 1]);
    uint4* dst = (uint4*)(xg + (r0 + r) * G4 + c0 + cg * 32);
    dst[0] = make_uint4(ow[0], ow[1], ow[2], ow[3]);
    dst[1] = make_uint4(ow[4], ow[5], ow[6], ow[7]);
    dst[2] = make_uint4(ow[8], ow[9], ow[10], ow[11]);
    dst[3] = make_uint4(ow[12], ow[13], ow[14], ow[15]);
}

// ---------------- stage 3: output projection (post-pass) -------------------
__global__ __launch_bounds__(256) void out_proj(
    const unsigned short* __restrict__ hs,  // [B,T,1024]; h(t) in first 256
    const float* __restrict__ Wout,         // [256,6]
    const float* __restrict__ bout,         // [6]
    float* __restrict__ out)                // [B,T,6]
{
    __shared__ float wt[Cc][Hh];
    const int tid = threadIdx.x;
    for (int i = tid; i < Cc * Hh; i += 256) wt[i % Cc][i / Cc] = Wout[i];
    __syncthreads();

    const int b = blockIdx.x;
    const int t = blockIdx.y * 256 + tid;
    const uint4* h4 = (const uint4*)(hs + ((long)b * Tt + t) * G4);
    float a0 = bout[0], a1 = bout[1], a2 = bout[2];
    float a3 = bout[3], a4 = bout[4], a5 = bout[5];
    #pragma unroll
    for (int j = 0; j < 32; ++j) {          // 8 h values per uint4
        uint4 hv = h4[j];
        const unsigned int hw[4] = { hv.x, hv.y, hv.z, hv.w };
        #pragma unroll
        for (int q = 0; q < 4; ++q) {
            float hlo = h2f((unsigned short)(hw[q] & 0xffff));
            float hhi = h2f((unsigned short)(hw[q] >> 16));
            int m = j * 8 + 2 * q;
            a0 += hlo * wt[0][m] + hhi * wt[0][m + 1];
            a1 += hlo * wt[1][m] + hhi * wt[1][m + 1];
            a2 += hlo * wt[2][m] + hhi * wt[2][m + 1];
            a3 += hlo * wt[3][m] + hhi * wt[3][m + 1];
            a4 += hlo * wt[4][m] + hhi * wt[4][m + 1];
            a5 += hlo * wt[5][m] + hhi * wt[5][m + 1];
        }
    }
    float* orow = out + ((long)b * Tt + t) * Cc;
    orow[0] = a0; orow[1] = a1; orow[2] = a2;
    orow[3] = a3; orow[4] = a4; orow[5] = a5;
}

// ---------------- stage 2: recurrence -------------------------------------
// pair i covers k = 2i,2i+1; cols A,B,C,D = gates i,f,g,o of unit tid.

#define WLOADV4(i) \
  const f16x2 wA_##i = f16x2{(_Float16)Wh[(2*(i))*G4 + colA], (_Float16)Wh[(2*(i)+1)*G4 + colA]}; \
  const f16x2 wB_##i = f16x2{(_Float16)Wh[(2*(i))*G4 + colB], (_Float16)Wh[(2*(i)+1)*G4 + colB]}; \
  const f16x2 wC_##i = f16x2{(_Float16)Wh[(2*(i))*G4 + colC], (_Float16)Wh[(2*(i)+1)*G4 + colC]}; \
  const f16x2 wD_##i = f16x2{(_Float16)Wh[(2*(i))*G4 + colD], (_Float16)Wh[(2*(i)+1)*G4 + colD]};

#define AW1(dst, cix, i) { \
    f16x2 t_ = f16x2{(_Float16)Wh[(2*(i))*G4 + (cix)], (_Float16)Wh[(2*(i)+1)*G4 + (cix)]}; \
    asm volatile("v_accvgpr_write_b32 %0, %1" : "=a"(dst) : "v"(__builtin_bit_cast(float, t_))); }

#define WLOADA4(i) \
  float awA_##i, awB_##i, awC_##i, awD_##i; \
  AW1(awA_##i, colA, i) AW1(awB_##i, colB, i) \
  AW1(awC_##i, colC, i) AW1(awD_##i, colD, i)

#define REPV32(M) \
  M(0) M(1) M(2) M(3) M(4) M(5) M(6) M(7) \
  M(8) M(9) M(10) M(11) M(12) M(13) M(14) M(15) \
  M(16) M(17) M(18) M(19) M(20) M(21) M(22) M(23) \
  M(24) M(25) M(26) M(27) M(28) M(29) M(30) M(31)

#define REPA64(M) \
  M(32) M(33) M(34) M(35) M(36) M(37) M(38) M(39) \
  M(40) M(41) M(42) M(43) M(44) M(45) M(46) M(47) \
  M(48) M(49) M(50) M(51) M(52) M(53) M(54) M(55) \
  M(56) M(57) M(58) M(59) M(60) M(61) M(62) M(63) \
  M(64) M(65) M(66) M(67) M(68) M(69) M(70) M(71) \
  M(72) M(73) M(74) M(75) M(76) M(77) M(78) M(79) \
  M(80) M(81) M(82) M(83) M(84) M(85) M(86) M(87) \
  M(88) M(89) M(90) M(91) M(92) M(93) M(94) M(95)

#define DOTPV(i, hh) { f16x2 h_ = (hh); \
    aA = dot2(h_, wA_##i, aA); aB = dot2(h_, wB_##i, aB); \
    aC = dot2(h_, wC_##i, aC); aD = dot2(h_, wD_##i, aD); }

#define GV(s, n, i0,i1,i2,i3) { \
    DOTPV(i0, bcf(s.x)) DOTPV(i1, bcf(s.y)) \
    DOTPV(i2, bcf(s.z)) DOTPV(i3, bcf(s.w)) \
    s = hvf4[n]; }

#define ARD(dst, src) \
    asm volatile("v_accvgpr_read_b32 %0, %1" : "=v"(dst) : "a"(src));

#define AREADG(bk, i0,i1,i2,i3) \
    ARD(qA##bk##_0, awA_##i0) ARD(qB##bk##_0, awB_##i0) ARD(qC##bk##_0, awC_##i0) ARD(qD##bk##_0, awD_##i0) \
    ARD(qA##bk##_1, awA_##i1) ARD(qB##bk##_1, awB_##i1) ARD(qC##bk##_1, awC_##i1) ARD(qD##bk##_1, awD_##i1) \
    ARD(qA##bk##_2, awA_##i2) ARD(qB##bk##_2, awB_##i2) ARD(qC##bk##_2, awC_##i2) ARD(qD##bk##_2, awD_##i2) \
    ARD(qA##bk##_3, awA_##i3) ARD(qB##bk##_3, awB_##i3) ARD(qC##bk##_3, awC_##i3) ARD(qD##bk##_3, awD_##i3)

#define ADOTSG(bk, hs) { \
    f16x2 h0 = bcf(hs.x), h1 = bcf(hs.y), h2 = bcf(hs.z), h3 = bcf(hs.w); \
    aA = dot2(h0, bcf(qA##bk##_0), aA); aB = dot2(h0, bcf(qB##bk##_0), aB); \
    aC = dot2(h0, bcf(qC##bk##_0), aC); aD = dot2(h0, bcf(qD##bk##_0), aD); \
    aA = dot2(h1, bcf(qA##bk##_1), aA); aB = dot2(h1, bcf(qB##bk##_1), aB); \
    aC = dot2(h1, bcf(qC##bk##_1), aC); aD = dot2(h1, bcf(qD##bk##_1), aD); \
    aA = dot2(h2, bcf(qA##bk##_2), aA); aB = dot2(h2, bcf(qB##bk##_2), aB); \
    aC = dot2(h2, bcf(qC##bk##_2), aC); aD = dot2(h2, bcf(qD##bk##_2), aD); \
    aA = dot2(h3, bcf(qA##bk##_3), aA); aB = dot2(h3, bcf(qB##bk##_3), aB); \
    aC = dot2(h3, bcf(qC##bk##_3), aC); aD = dot2(h3, bcf(qD##bk##_3), aD); }

#define TWL(s, jq) { twA##s = wl4[jq][colA]; twB##s = wl4[jq][colB]; \
                     twC##s = wl4[jq][colC]; twD##s = wl4[jq][colD]; }

#define GT(hs, s) { \
    f16x2 h0 = bcf(hs.x), h1 = bcf(hs.y), h2 = bcf(hs.z), h3 = bcf(hs.w); \
    aA = dot2(h0, bcu(twA##s.x), aA); aA = dot2(h1, bcu(twA##s.y), aA); \
    aA = dot2(h2, bcu(twA##s.z), aA); aA = dot2(h3, bcu(twA##s.w), aA); \
    aB = dot2(h0, bcu(twB##s.x), aB); aB = dot2(h1, bcu(twB##s.y), aB); \
    aB = dot2(h2, bcu(twB##s.z), aB); aB = dot2(h3, bcu(twB##s.w), aB); \
    aC = dot2(h0, bcu(twC##s.x), aC); aC = dot2(h1, bcu(twC##s.y), aC); \
    aC = dot2(h2, bcu(twC##s.z), aC); aC = dot2(h3, bcu(twC##s.w), aC); \
    aD = dot2(h0, bcu(twD##s.x), aD); aD = dot2(h1, bcu(twD##s.y), aD); \
    aD = dot2(h2, bcu(twD##s.z), aD); aD = dot2(h3, bcu(twD##s.w), aD); }

__global__ __launch_bounds__(256, 1) void lstm_xg(
    unsigned short* __restrict__ xg,        // [B,T,1024] f16 in+h out
    const float* __restrict__ Wh)           // [H,4H]
{
    __shared__ alignas(16) unsigned short h_buf[2][Hh];  // double-buffered h
    __shared__ uint4 wl4[8][G4];       // tail pairs 96..127, 128 KB

    const int tid  = threadIdx.x;
    const int b    = blockIdx.x;
    const int colA = tid;          // gate i of unit tid
    const int colB = tid + 256;    // f
    const int colC = tid + 512;    // g
    const int colD = tid + 768;    // o

    // ---- prologue: 128 V-regs + 256 AGPRs + packed LDS tail ----
    REPV32(WLOADV4)
    REPA64(WLOADA4)

    #pragma unroll
    for (int jq = 0; jq < 8; ++jq) {   // tail: k rows 192+8jq .. 192+8jq+7
        const int kb = 192 + 8 * jq;
        wl4[jq][colA] = make_uint4(
            packh(Wh[(kb+0)*G4 + colA], Wh[(kb+1)*G4 + colA]),
            packh(Wh[(kb+2)*G4 + colA], Wh[(kb+3)*G4 + colA]),
            packh(Wh[(kb+4)*G4 + colA], Wh[(kb+5)*G4 + colA]),
            packh(Wh[(kb+6)*G4 + colA], Wh[(kb+7)*G4 + colA]));
        wl4[jq][colB] = make_uint4(
            packh(Wh[(kb+0)*G4 + colB], Wh[(kb+1)*G4 + colB]),
            packh(Wh[(kb+2)*G4 + colB], Wh[(kb+3)*G4 + colB]),
            packh(Wh[(kb+4)*G4 + colB], Wh[(kb+5)*G4 + colB]),
            packh(Wh[(kb+6)*G4 + colB], Wh[(kb+7)*G4 + colB]));
        wl4[jq][colC] = make_uint4(
            packh(Wh[(kb+0)*G4 + colC], Wh[(kb+1)*G4 + colC]),
            packh(Wh[(kb+2)*G4 + colC], Wh[(kb+3)*G4 + colC]),
            packh(Wh[(kb+4)*G4 + colC], Wh[(kb+5)*G4 + colC]),
            packh(Wh[(kb+6)*G4 + colC], Wh[(kb+7)*G4 + colC]));
        wl4[jq][colD] = make_uint4(
            packh(Wh[(kb+0)*G4 + colD], Wh[(kb+1)*G4 + colD]),
            packh(Wh[(kb+2)*G4 + colD], Wh[(kb+3)*G4 + colD]),
            packh(Wh[(kb+4)*G4 + colD], Wh[(kb+5)*G4 + colD]),
            packh(Wh[(kb+6)*G4 + colD], Wh[(kb+7)*G4 + colD]));
    }
    h_buf[0][tid] = 0;

    unsigned short* xgB = xg + (long)b * Tt * G4;
    unsigned short xgA = xgB[colA], xgBv = xgB[colB];
    unsigned short xgC = xgB[colC], xgD = xgB[colD];
    float c_state = 0.0f;
    int par = 0;
    __syncthreads();

    // ---- time loop: one barrier/step, no projection ----
    for (int t = 0; t < Tt; ++t) {
        unsigned short nA = 0, nB = 0, nC = 0, nD = 0;
        if (t + 1 < Tt) {
            const unsigned short* xn = xgB + (long)(t + 1) * G4;
            nA = xn[colA]; nB = xn[colB]; nC = xn[colC]; nD = xn[colD];
        }

        const float4* hvf4 = (const float4*)h_buf[par];  // h(t-1), broadcast
        float aA = 0.f, aB = 0.f, aC = 0.f, aD = 0.f;

        float qA0_0, qB0_0, qC0_0, qD0_0, qA0_1, qB0_1, qC0_1, qD0_1;
        float qA0_2, qB0_2, qC0_2, qD0_2, qA0_3, qB0_3, qC0_3, qD0_3;
        float qA1_0, qB1_0, qC1_0, qD1_0, qA1_1, qB1_1, qC1_1, qD1_1;
        float qA1_2, qB1_2, qC1_2, qD1_2, qA1_3, qB1_3, qC1_3, qD1_3;
        uint4 twA0, twB0, twC0, twD0, twA1, twB1, twC1, twD1;
        uint4 twA2, twB2, twC2, twD2;

        // 4 rotating h slots, primed 4 groups deep
        float4 hs0 = hvf4[0], hs1 = hvf4[1], hs2 = hvf4[2], hs3 = hvf4[3];

        // V groups: pairs 0..31 (h groups 0..7)
        GV(hs0, 4,   0, 1, 2, 3)   GV(hs1, 5,   4, 5, 6, 7)
        GV(hs2, 6,   8, 9,10,11)   GV(hs3, 7,  12,13,14,15)
        GV(hs0, 8,  16,17,18,19)   GV(hs1, 9,  20,21,22,23)
        GV(hs2, 10, 24,25,26,27)   GV(hs3, 11, 28,29,30,31)

        // A bank pipeline: reads for group k+1 precede dots of group k
        AREADG(0, 32,33,34,35)
        AREADG(1, 36,37,38,39)  ADOTSG(0, hs0)  hs0 = hvf4[12];
        AREADG(0, 40,41,42,43)  ADOTSG(1, hs1)  hs1 = hvf4[13];
        AREADG(1, 44,45,46,47)  ADOTSG(0, hs2)  hs2 = hvf4[14];
        AREADG(0, 48,49,50,51)  ADOTSG(1, hs3)  hs3 = hvf4[15];
        AREADG(1, 52,53,54,55)  ADOTSG(0, hs0)  hs0 = hvf4[16];
        AREADG(0, 56,57,58,59)  ADOTSG(1, hs1)  hs1 = hvf4[17];
        AREADG(1, 60,61,62,63)  ADOTSG(0, hs2)  hs2 = hvf4[18];
        AREADG(0, 64,65,66,67)  ADOTSG(1, hs3)  hs3 = hvf4[19];
        AREADG(1, 68,69,70,71)  ADOTSG(0, hs0)  hs0 = hvf4[20];
        AREADG(0, 72,73,74,75)  ADOTSG(1, hs1)  hs1 = hvf4[21];
        TWL(0, 0)
        AREADG(1, 76,77,78,79)  ADOTSG(0, hs2)  hs2 = hvf4[22];
        AREADG(0, 80,81,82,83)  ADOTSG(1, hs3)  hs3 = hvf4[23];
        TWL(1, 1)
        AREADG(1, 84,85,86,87)  ADOTSG(0, hs0)  hs0 = hvf4[24];
        AREADG(0, 88,89,90,91)  ADOTSG(1, hs1)  hs1 = hvf4[25];
        TWL(2, 2)
        AREADG(1, 92,93,94,95)  ADOTSG(0, hs2)  hs2 = hvf4[26];
                                ADOTSG(1, hs3)  hs3 = hvf4[27];

        // tail: pairs 96..127 (h groups 24..31), 3-buffer rotation
        GT(hs0, 0)  TWL(0, 3)  hs0 = hvf4[28];
        GT(hs1, 1)  TWL(1, 4)  hs1 = hvf4[29];
        GT(hs2, 2)  TWL(2, 5)  hs2 = hvf4[30];
        GT(hs3, 0)  TWL(0, 6)  hs3 = hvf4[31];
        GT(hs0, 1)  TWL(1, 7)
        GT(hs1, 2)
        GT(hs2, 0)
        GT(hs3, 1)

        float ig = sigm(h2f(xgA) + aA);
        float fg = sigm(h2f(xgBv) + aB);
        float gg = tanh_fast(h2f(xgC) + aC);
        float og = sigm(h2f(xgD) + aD);
        c_state = fg * c_state + ig * gg;
        float hval = og * tanh_fast(c_state);

        unsigned short hb = f2h(hval);
        h_buf[par ^ 1][tid] = hb;         // LDS for next step
        xgB[(long)t * G4 + tid] = hb;     // global (row t already consumed)
        __syncthreads();                   // h(t) visible

        xgA = nA; xgBv = nB; xgC = nC; xgD = nD;
        par ^= 1;
    }
}

// ---------------- fallback: R2 single-block kernel (no ws needed) ----------
__global__ __launch_bounds__(1024) void lstm_fused(
    const float* __restrict__ x, const float* __restrict__ Wx,
    const float* __restrict__ Wh, const float* __restrict__ bias,
    const float* __restrict__ Wout, const float* __restrict__ bout,
    float* __restrict__ out)
{
    __shared__ float h_lds[Hh];
    __shared__ float gates_lds[G4];
    __shared__ float x_lds[2][Dd];
    __shared__ float wout_t[Cc][Hh];
    __shared__ float bout_l[Cc];
    const int tid = threadIdx.x;
    const int b   = blockIdx.x;
    float wx[Dd];
    #pragma unroll
    for (int d = 0; d < Dd; ++d) wx[d] = Wx[d * G4 + tid];
    const float bj = bias[tid];
    if (tid < Hh) h_lds[tid] = 0.0f;
    for (int i = tid; i < Cc * Hh; i += 1024) wout_t[i % Cc][i / Cc] = Wout[i];
    if (tid < Cc) bout_l[tid] = bout[tid];
    const float* xB = x + (long)b * Tt * Dd;
    if (tid < Dd) x_lds[0][tid] = xB[tid];
    float c_state = 0.0f;
    __syncthreads();
    const float* WhB = Wh + tid;
    for (int t = 0; t < Tt; ++t) {
        float gg = bj;
        const float* xr = x_lds[t & 1];
        #pragma unroll
        for (int d = 0; d < Dd; ++d) gg += xr[d] * wx[d];
        #pragma unroll 8
        for (int k = 0; k < Hh; ++k) gg += h_lds[k] * WhB[k * G4];
        float a;
        if (tid < 2 * Hh)      a = 1.0f / (1.0f + expf(-gg));
        else if (tid < 3 * Hh) a = tanhf(gg);
        else                   a = 1.0f / (1.0f + expf(-gg));
        gates_lds[tid] = a;
        __syncthreads();
        if (tid < Hh) {
            float iv = gates_lds[tid], fv = gates_lds[tid + Hh];
            float gv = gates_lds[tid + 2 * Hh], ov = gates_lds[tid + 3 * Hh];
            c_state = fv * c_state + iv * gv;
            h_lds[tid] = ov * tanhf(c_state);
        } else if (tid >= 384 && tid < 448) {
            int tn = t + 1;
            if (tn < Tt) x_lds[tn & 1][tid - 384] = xB[(long)tn * Dd + (tid - 384)];
        }
        __syncthreads();
        const int w = tid >> 6, l = tid & 63;
        if (w < Cc) {
            float p = 0.0f;
            #pragma unroll
            for (int qq = 0; qq < 4; ++qq) p += h_lds[l + 64 * qq] * wout_t[w][l + 64 * qq];
            #pragma unroll
            for (int off = 32; off > 0; off >>= 1) p += __shfl_down(p, off);
            if (l == 0) out[((long)b * Tt + t) * Cc + w] = p + bout_l[w];
        }
    }
}

extern "C" void kernel_launch(void* const* d_in, const int* in_sizes, int n_in,
                              void* d_out, int out_size, void* d_ws, size_t ws_size,
                              hipStream_t stream) {
    const float* x    = (const float*)d_in[0];
    const float* Wx   = (const float*)d_in[1];
    const float* Wh   = (const float*)d_in[2];
    const float* bvec = (const float*)d_in[3];
    const float* Wout = (const float*)d_in[4];
    const float* bout = (const float*)d_in[5];
    float* outp = (float*)d_out;

    if (ws_size >= XG_BYTES) {
        unsigned short* xgws = (unsigned short*)d_ws;
        xg_gemm<<<dim3(BT / 32, 4), dim3(256), 0, stream>>>(x, Wx, bvec, xgws);
        lstm_xg<<<dim3(128), dim3(256), 0, stream>>>(xgws, Wh);
        out_proj<<<dim3(128, 4), dim3(256), 0, stream>>>(xgws, Wout, bout, outp);
    } else {
        lstm_fused<<<dim3(128), dim3(1024), 0, stream>>>(x, Wx, Wh, bvec, Wout, bout, outp);
    }
}

// Round 19
// 2253.878 us; speedup vs baseline: 2.0520x; 1.1121x over previous
//
#include <hip/hip_runtime.h>
#include <math.h>

// LSTM B=128,T=1024,D=64,H=256,C=6 — R19: R18 (proven lstm_xg + out_proj)
// + rebuilt xg_gemm (f16-packed weights, dot2, 2 rows/thread).
//
// R18 landed 2.51ms total: lstm 2.13ms (VALUBusy 36%, bank conflicts 0 —
// near the dot2-structure floor), xg+proj = 371us. This round attacks xg:
// old xg_gemm was LDS-instruction-bound (576 LDS instr/thread for 2048 FMA).
// New: Wx staged as packed f16x2 k-pairs [32][256] (32KB), x as f16x2
// [64][33] uint (padded, conflict-free), thread = 2 rows x 32 cols ->
// 320 LDS instr + 2048 dot2. lstm_xg / out_proj byte-identical to R18.

#define Tt 1024
#define Dd 64
#define Hh 256
#define G4 1024
#define Cc 6
#define BT (128 * 1024)
#define XG_BYTES ((size_t)BT * G4 * 2)   // 256 MB f16

typedef _Float16 f16x2 __attribute__((ext_vector_type(2)));

__device__ __forceinline__ float dot2(f16x2 a, f16x2 b, float c) {
#if __has_builtin(__builtin_amdgcn_fdot2)
    return __builtin_amdgcn_fdot2(a, b, c, false);
#else
    return c + (float)a.x * (float)b.x + (float)a.y * (float)b.y;
#endif
}
__device__ __forceinline__ float sigm(float p) { return 1.0f / (1.0f + __expf(-p)); }
__device__ __forceinline__ float tanh_fast(float p) {
    return 1.0f - 2.0f / (__expf(2.0f * p) + 1.0f);
}
__device__ __forceinline__ unsigned short f2h(float v) {
    _Float16 h = (_Float16)v;
    return __builtin_bit_cast(unsigned short, h);
}
__device__ __forceinline__ float h2f(unsigned short u) {
    return (float)__builtin_bit_cast(_Float16, u);
}
__device__ __forceinline__ f16x2 bcf(float v) { return __builtin_bit_cast(f16x2, v); }
__device__ __forceinline__ f16x2 bcu(unsigned int v) { return __builtin_bit_cast(f16x2, v); }
__device__ __forceinline__ unsigned int packh(float a, float b) {
    return (unsigned int)f2h(a) | ((unsigned int)f2h(b) << 16);
}

// ---------------- stage 1: xg = x @ Wx + bias (f16 dot2, R19) --------------
// Block: 64 rows x 256 cols. Thread (tr=tid&31, cg=tid>>5): rows {tr, tr+32},
// cols cg*32..+31. Wx packed f16x2 k-pairs in LDS; x packed f16x2, padded.
__global__ __launch_bounds__(256) void xg_gemm(
    const float* __restrict__ x, const float* __restrict__ Wx,
    const float* __restrict__ bias, unsigned short* __restrict__ xg)
{
    __shared__ unsigned int xs[64][33];    // x rows as f16x2 pairs (+pad)
    __shared__ unsigned int wsl[32][256];  // Wx[2kp..2kp+1][c0..c0+255] packed

    const int tid = threadIdx.x;
    const long r0 = (long)blockIdx.x * 64;
    const int  c0 = blockIdx.y * 256;

    // stage x tile: 64 rows x 16 float4 -> packed pairs
    #pragma unroll
    for (int it = 0; it < 4; ++it) {
        int i = tid + it * 256;            // i in [0,1024)
        int row = i >> 4, f4 = i & 15;
        float4 v = *(const float4*)(x + (r0 + row) * Dd + f4 * 4);
        xs[row][2 * f4]     = packh(v.x, v.y);
        xs[row][2 * f4 + 1] = packh(v.z, v.w);
    }
    // stage Wx slice: rows 2kp,2kp+1 x 4 cols -> packed
    #pragma unroll
    for (int it = 0; it < 8; ++it) {
        int i = tid + it * 256;            // i in [0,2048)
        int kp = i >> 6, cq = i & 63;
        float4 a = *(const float4*)(Wx + (long)(2 * kp) * G4 + c0 + cq * 4);
        float4 b = *(const float4*)(Wx + (long)(2 * kp + 1) * G4 + c0 + cq * 4);
        wsl[kp][cq * 4 + 0] = packh(a.x, b.x);
        wsl[kp][cq * 4 + 1] = packh(a.y, b.y);
        wsl[kp][cq * 4 + 2] = packh(a.z, b.z);
        wsl[kp][cq * 4 + 3] = packh(a.w, b.w);
    }
    __syncthreads();

    const int tr = tid & 31, cg = tid >> 5;
    float acc0[32], acc1[32];
    #pragma unroll
    for (int c = 0; c < 32; ++c) {
        float bv = bias[c0 + cg * 32 + c];
        acc0[c] = bv; acc1[c] = bv;
    }
    for (int kp = 0; kp < 32; ++kp) {
        f16x2 u0 = bcu(xs[tr][kp]);
        f16x2 u1 = bcu(xs[tr + 32][kp]);
        const uint4* wr = (const uint4*)&wsl[kp][cg * 32];
        #pragma unroll
        for (int q = 0; q < 8; ++q) {
            uint4 w = wr[q];
            acc0[4*q+0] = dot2(u0, bcu(w.x), acc0[4*q+0]);
            acc0[4*q+1] = dot2(u0, bcu(w.y), acc0[4*q+1]);
            acc0[4*q+2] = dot2(u0, bcu(w.z), acc0[4*q+2]);
            acc0[4*q+3] = dot2(u0, bcu(w.w), acc0[4*q+3]);
            acc1[4*q+0] = dot2(u1, bcu(w.x), acc1[4*q+0]);
            acc1[4*q+1] = dot2(u1, bcu(w.y), acc1[4*q+1]);
            acc1[4*q+2] = dot2(u1, bcu(w.z), acc1[4*q+2]);
            acc1[4*q+3] = dot2(u1, bcu(w.w), acc1[4*q+3]);
        }
    }
    // store both rows, packed f16
    {
        unsigned int ow[16];
        #pragma unroll
        for (int c2 = 0; c2 < 16; ++c2) ow[c2] = packh(acc0[2*c2], acc0[2*c2+1]);
        uint4* dst = (uint4*)(xg + (r0 + tr) * G4 + c0 + cg * 32);
        dst[0] = make_uint4(ow[0], ow[1], ow[2], ow[3]);
        dst[1] = make_uint4(ow[4], ow[5], ow[6], ow[7]);
        dst[2] = make_uint4(ow[8], ow[9], ow[10], ow[11]);
        dst[3] = make_uint4(ow[12], ow[13], ow[14], ow[15]);
    }
    {
        unsigned int ow[16];
        #pragma unroll
        for (int c2 = 0; c2 < 16; ++c2) ow[c2] = packh(acc1[2*c2], acc1[2*c2+1]);
        uint4* dst = (uint4*)(xg + (r0 + tr + 32) * G4 + c0 + cg * 32);
        dst[0] = make_uint4(ow[0], ow[1], ow[2], ow[3]);
        dst[1] = make_uint4(ow[4], ow[5], ow[6], ow[7]);
        dst[2] = make_uint4(ow[8], ow[9], ow[10], ow[11]);
        dst[3] = make_uint4(ow[12], ow[13], ow[14], ow[15]);
    }
}

// ---------------- stage 3: output projection (post-pass, R17) --------------
__global__ __launch_bounds__(256) void out_proj(
    const unsigned short* __restrict__ hs,  // [B,T,1024]; h(t) in first 256
    const float* __restrict__ Wout,         // [256,6]
    const float* __restrict__ bout,         // [6]
    float* __restrict__ out)                // [B,T,6]
{
    __shared__ float wt[Cc][Hh];
    const int tid = threadIdx.x;
    for (int i = tid; i < Cc * Hh; i += 256) wt[i % Cc][i / Cc] = Wout[i];
    __syncthreads();

    const int b = blockIdx.x;
    const int t = blockIdx.y * 256 + tid;
    const uint4* h4 = (const uint4*)(hs + ((long)b * Tt + t) * G4);
    float a0 = bout[0], a1 = bout[1], a2 = bout[2];
    float a3 = bout[3], a4 = bout[4], a5 = bout[5];
    #pragma unroll
    for (int j = 0; j < 32; ++j) {
        uint4 hv = h4[j];
        const unsigned int hw[4] = { hv.x, hv.y, hv.z, hv.w };
        #pragma unroll
        for (int q = 0; q < 4; ++q) {
            float hlo = h2f((unsigned short)(hw[q] & 0xffff));
            float hhi = h2f((unsigned short)(hw[q] >> 16));
            int m = j * 8 + 2 * q;
            a0 += hlo * wt[0][m] + hhi * wt[0][m + 1];
            a1 += hlo * wt[1][m] + hhi * wt[1][m + 1];
            a2 += hlo * wt[2][m] + hhi * wt[2][m + 1];
            a3 += hlo * wt[3][m] + hhi * wt[3][m + 1];
            a4 += hlo * wt[4][m] + hhi * wt[4][m + 1];
            a5 += hlo * wt[5][m] + hhi * wt[5][m + 1];
        }
    }
    float* orow = out + ((long)b * Tt + t) * Cc;
    orow[0] = a0; orow[1] = a1; orow[2] = a2;
    orow[3] = a3; orow[4] = a4; orow[5] = a5;
}

// ---------------- stage 2: recurrence (R17/R18, byte-identical) ------------
#define WLOADV4(i) \
  const f16x2 wA_##i = f16x2{(_Float16)Wh[(2*(i))*G4 + colA], (_Float16)Wh[(2*(i)+1)*G4 + colA]}; \
  const f16x2 wB_##i = f16x2{(_Float16)Wh[(2*(i))*G4 + colB], (_Float16)Wh[(2*(i)+1)*G4 + colB]}; \
  const f16x2 wC_##i = f16x2{(_Float16)Wh[(2*(i))*G4 + colC], (_Float16)Wh[(2*(i)+1)*G4 + colC]}; \
  const f16x2 wD_##i = f16x2{(_Float16)Wh[(2*(i))*G4 + colD], (_Float16)Wh[(2*(i)+1)*G4 + colD]};

#define AW1(dst, cix, i) { \
    f16x2 t_ = f16x2{(_Float16)Wh[(2*(i))*G4 + (cix)], (_Float16)Wh[(2*(i)+1)*G4 + (cix)]}; \
    asm volatile("v_accvgpr_write_b32 %0, %1" : "=a"(dst) : "v"(__builtin_bit_cast(float, t_))); }

#define WLOADA4(i) \
  float awA_##i, awB_##i, awC_##i, awD_##i; \
  AW1(awA_##i, colA, i) AW1(awB_##i, colB, i) \
  AW1(awC_##i, colC, i) AW1(awD_##i, colD, i)

#define REPV32(M) \
  M(0) M(1) M(2) M(3) M(4) M(5) M(6) M(7) \
  M(8) M(9) M(10) M(11) M(12) M(13) M(14) M(15) \
  M(16) M(17) M(18) M(19) M(20) M(21) M(22) M(23) \
  M(24) M(25) M(26) M(27) M(28) M(29) M(30) M(31)

#define REPA64(M) \
  M(32) M(33) M(34) M(35) M(36) M(37) M(38) M(39) \
  M(40) M(41) M(42) M(43) M(44) M(45) M(46) M(47) \
  M(48) M(49) M(50) M(51) M(52) M(53) M(54) M(55) \
  M(56) M(57) M(58) M(59) M(60) M(61) M(62) M(63) \
  M(64) M(65) M(66) M(67) M(68) M(69) M(70) M(71) \
  M(72) M(73) M(74) M(75) M(76) M(77) M(78) M(79) \
  M(80) M(81) M(82) M(83) M(84) M(85) M(86) M(87) \
  M(88) M(89) M(90) M(91) M(92) M(93) M(94) M(95)

#define DOTPV(i, hh) { f16x2 h_ = (hh); \
    aA = dot2(h_, wA_##i, aA); aB = dot2(h_, wB_##i, aB); \
    aC = dot2(h_, wC_##i, aC); aD = dot2(h_, wD_##i, aD); }

#define GV(s, n, i0,i1,i2,i3) { \
    DOTPV(i0, bcf(s.x)) DOTPV(i1, bcf(s.y)) \
    DOTPV(i2, bcf(s.z)) DOTPV(i3, bcf(s.w)) \
    s = hvf4[n]; }

#define ARD(dst, src) \
    asm volatile("v_accvgpr_read_b32 %0, %1" : "=v"(dst) : "a"(src));

#define AREADG(bk, i0,i1,i2,i3) \
    ARD(qA##bk##_0, awA_##i0) ARD(qB##bk##_0, awB_##i0) ARD(qC##bk##_0, awC_##i0) ARD(qD##bk##_0, awD_##i0) \
    ARD(qA##bk##_1, awA_##i1) ARD(qB##bk##_1, awB_##i1) ARD(qC##bk##_1, awC_##i1) ARD(qD##bk##_1, awD_##i1) \
    ARD(qA##bk##_2, awA_##i2) ARD(qB##bk##_2, awB_##i2) ARD(qC##bk##_2, awC_##i2) ARD(qD##bk##_2, awD_##i2) \
    ARD(qA##bk##_3, awA_##i3) ARD(qB##bk##_3, awB_##i3) ARD(qC##bk##_3, awC_##i3) ARD(qD##bk##_3, awD_##i3)

#define ADOTSG(bk, hs) { \
    f16x2 h0 = bcf(hs.x), h1 = bcf(hs.y), h2 = bcf(hs.z), h3 = bcf(hs.w); \
    aA = dot2(h0, bcf(qA##bk##_0), aA); aB = dot2(h0, bcf(qB##bk##_0), aB); \
    aC = dot2(h0, bcf(qC##bk##_0), aC); aD = dot2(h0, bcf(qD##bk##_0), aD); \
    aA = dot2(h1, bcf(qA##bk##_1), aA); aB = dot2(h1, bcf(qB##bk##_1), aB); \
    aC = dot2(h1, bcf(qC##bk##_1), aC); aD = dot2(h1, bcf(qD##bk##_1), aD); \
    aA = dot2(h2, bcf(qA##bk##_2), aA); aB = dot2(h2, bcf(qB##bk##_2), aB); \
    aC = dot2(h2, bcf(qC##bk##_2), aC); aD = dot2(h2, bcf(qD##bk##_2), aD); \
    aA = dot2(h3, bcf(qA##bk##_3), aA); aB = dot2(h3, bcf(qB##bk##_3), aB); \
    aC = dot2(h3, bcf(qC##bk##_3), aC); aD = dot2(h3, bcf(qD##bk##_3), aD); }

#define TWL(s, jq) { twA##s = wl4[jq][colA]; twB##s = wl4[jq][colB]; \
                     twC##s = wl4[jq][colC]; twD##s = wl4[jq][colD]; }

#define GT(hs, s) { \
    f16x2 h0 = bcf(hs.x), h1 = bcf(hs.y), h2 = bcf(hs.z), h3 = bcf(hs.w); \
    aA = dot2(h0, bcu(twA##s.x), aA); aA = dot2(h1, bcu(twA##s.y), aA); \
    aA = dot2(h2, bcu(twA##s.z), aA); aA = dot2(h3, bcu(twA##s.w), aA); \
    aB = dot2(h0, bcu(twB##s.x), aB); aB = dot2(h1, bcu(twB##s.y), aB); \
    aB = dot2(h2, bcu(twB##s.z), aB); aB = dot2(h3, bcu(twB##s.w), aB); \
    aC = dot2(h0, bcu(twC##s.x), aC); aC = dot2(h1, bcu(twC##s.y), aC); \
    aC = dot2(h2, bcu(twC##s.z), aC); aC = dot2(h3, bcu(twC##s.w), aC); \
    aD = dot2(h0, bcu(twD##s.x), aD); aD = dot2(h1, bcu(twD##s.y), aD); \
    aD = dot2(h2, bcu(twD##s.z), aD); aD = dot2(h3, bcu(twD##s.w), aD); }

__global__ __launch_bounds__(256, 1) void lstm_xg(
    unsigned short* __restrict__ xg,        // [B,T,1024] f16 in + h out
    const float* __restrict__ Wh)           // [H,4H]
{
    __shared__ alignas(16) unsigned short h_buf[2][Hh];
    __shared__ uint4 wl4[8][G4];       // tail pairs 96..127, 128 KB

    const int tid  = threadIdx.x;
    const int b    = blockIdx.x;
    const int colA = tid;
    const int colB = tid + 256;
    const int colC = tid + 512;
    const int colD = tid + 768;

    REPV32(WLOADV4)
    REPA64(WLOADA4)

    #pragma unroll
    for (int jq = 0; jq < 8; ++jq) {
        const int kb = 192 + 8 * jq;
        wl4[jq][colA] = make_uint4(
            packh(Wh[(kb+0)*G4 + colA], Wh[(kb+1)*G4 + colA]),
            packh(Wh[(kb+2)*G4 + colA], Wh[(kb+3)*G4 + colA]),
            packh(Wh[(kb+4)*G4 + colA], Wh[(kb+5)*G4 + colA]),
            packh(Wh[(kb+6)*G4 + colA], Wh[(kb+7)*G4 + colA]));
        wl4[jq][colB] = make_uint4(
            packh(Wh[(kb+0)*G4 + colB], Wh[(kb+1)*G4 + colB]),
            packh(Wh[(kb+2)*G4 + colB], Wh[(kb+3)*G4 + colB]),
            packh(Wh[(kb+4)*G4 + colB], Wh[(kb+5)*G4 + colB]),
            packh(Wh[(kb+6)*G4 + colB], Wh[(kb+7)*G4 + colB]));
        wl4[jq][colC] = make_uint4(
            packh(Wh[(kb+0)*G4 + colC], Wh[(kb+1)*G4 + colC]),
            packh(Wh[(kb+2)*G4 + colC], Wh[(kb+3)*G4 + colC]),
            packh(Wh[(kb+4)*G4 + colC], Wh[(kb+5)*G4 + colC]),
            packh(Wh[(kb+6)*G4 + colC], Wh[(kb+7)*G4 + colC]));
        wl4[jq][colD] = make_uint4(
            packh(Wh[(kb+0)*G4 + colD], Wh[(kb+1)*G4 + colD]),
            packh(Wh[(kb+2)*G4 + colD], Wh[(kb+3)*G4 + colD]),
            packh(Wh[(kb+4)*G4 + colD], Wh[(kb+5)*G4 + colD]),
            packh(Wh[(kb+6)*G4 + colD], Wh[(kb+7)*G4 + colD]));
    }
    h_buf[0][tid] = 0;

    unsigned short* xgB = xg + (long)b * Tt * G4;
    unsigned short xgA = xgB[colA], xgBv = xgB[colB];
    unsigned short xgC = xgB[colC], xgD = xgB[colD];
    float c_state = 0.0f;
    int par = 0;
    __syncthreads();

    for (int t = 0; t < Tt; ++t) {
        unsigned short nA = 0, nB = 0, nC = 0, nD = 0;
        if (t + 1 < Tt) {
            const unsigned short* xn = xgB + (long)(t + 1) * G4;
            nA = xn[colA]; nB = xn[colB]; nC = xn[colC]; nD = xn[colD];
        }

        const float4* hvf4 = (const float4*)h_buf[par];
        float aA = 0.f, aB = 0.f, aC = 0.f, aD = 0.f;

        float qA0_0, qB0_0, qC0_0, qD0_0, qA0_1, qB0_1, qC0_1, qD0_1;
        float qA0_2, qB0_2, qC0_2, qD0_2, qA0_3, qB0_3, qC0_3, qD0_3;
        float qA1_0, qB1_0, qC1_0, qD1_0, qA1_1, qB1_1, qC1_1, qD1_1;
        float qA1_2, qB1_2, qC1_2, qD1_2, qA1_3, qB1_3, qC1_3, qD1_3;
        uint4 twA0, twB0, twC0, twD0, twA1, twB1, twC1, twD1;
        uint4 twA2, twB2, twC2, twD2;

        float4 hs0 = hvf4[0], hs1 = hvf4[1], hs2 = hvf4[2], hs3 = hvf4[3];

        GV(hs0, 4,   0, 1, 2, 3)   GV(hs1, 5,   4, 5, 6, 7)
        GV(hs2, 6,   8, 9,10,11)   GV(hs3, 7,  12,13,14,15)
        GV(hs0, 8,  16,17,18,19)   GV(hs1, 9,  20,21,22,23)
        GV(hs2, 10, 24,25,26,27)   GV(hs3, 11, 28,29,30,31)

        AREADG(0, 32,33,34,35)
        AREADG(1, 36,37,38,39)  ADOTSG(0, hs0)  hs0 = hvf4[12];
        AREADG(0, 40,41,42,43)  ADOTSG(1, hs1)  hs1 = hvf4[13];
        AREADG(1, 44,45,46,47)  ADOTSG(0, hs2)  hs2 = hvf4[14];
        AREADG(0, 48,49,50,51)  ADOTSG(1, hs3)  hs3 = hvf4[15];
        AREADG(1, 52,53,54,55)  ADOTSG(0, hs0)  hs0 = hvf4[16];
        AREADG(0, 56,57,58,59)  ADOTSG(1, hs1)  hs1 = hvf4[17];
        AREADG(1, 60,61,62,63)  ADOTSG(0, hs2)  hs2 = hvf4[18];
        AREADG(0, 64,65,66,67)  ADOTSG(1, hs3)  hs3 = hvf4[19];
        AREADG(1, 68,69,70,71)  ADOTSG(0, hs0)  hs0 = hvf4[20];
        AREADG(0, 72,73,74,75)  ADOTSG(1, hs1)  hs1 = hvf4[21];
        TWL(0, 0)
        AREADG(1, 76,77,78,79)  ADOTSG(0, hs2)  hs2 = hvf4[22];
        AREADG(0, 80,81,82,83)  ADOTSG(1, hs3)  hs3 = hvf4[23];
        TWL(1, 1)
        AREADG(1, 84,85,86,87)  ADOTSG(0, hs0)  hs0 = hvf4[24];
        AREADG(0, 88,89,90,91)  ADOTSG(1, hs1)  hs1 = hvf4[25];
        TWL(2, 2)
        AREADG(1, 92,93,94,95)  ADOTSG(0, hs2)  hs2 = hvf4[26];
                                ADOTSG(1, hs3)  hs3 = hvf4[27];

        GT(hs0, 0)  TWL(0, 3)  hs0 = hvf4[28];
        GT(hs1, 1)  TWL(1, 4)  hs1 = hvf4[29];
        GT(hs2, 2)  TWL(2, 5)  hs2 = hvf4[30];
        GT(hs3, 0)  TWL(0, 6)  hs3 = hvf4[31];
        GT(hs0, 1)  TWL(1, 7)
        GT(hs1, 2)
        GT(hs2, 0)
        GT(hs3, 1)

        float ig = sigm(h2f(xgA) + aA);
        float fg = sigm(h2f(xgBv) + aB);
        float gg = tanh_fast(h2f(xgC) + aC);
        float og = sigm(h2f(xgD) + aD);
        c_state = fg * c_state + ig * gg;
        float hval = og * tanh_fast(c_state);

        unsigned short hb = f2h(hval);
        h_buf[par ^ 1][tid] = hb;
        xgB[(long)t * G4 + tid] = hb;
        __syncthreads();

        xgA = nA; xgBv = nB; xgC = nC; xgD = nD;
        par ^= 1;
    }
}

// ---------------- fallback: R2 single-block kernel (no ws needed) ----------
__global__ __launch_bounds__(1024) void lstm_fused(
    const float* __restrict__ x, const float* __restrict__ Wx,
    const float* __restrict__ Wh, const float* __restrict__ bias,
    const float* __restrict__ Wout, const float* __restrict__ bout,
    float* __restrict__ out)
{
    __shared__ float h_lds[Hh];
    __shared__ float gates_lds[G4];
    __shared__ float x_lds[2][Dd];
    __shared__ float wout_t[Cc][Hh];
    __shared__ float bout_l[Cc];
    const int tid = threadIdx.x;
    const int b   = blockIdx.x;
    float wx[Dd];
    #pragma unroll
    for (int d = 0; d < Dd; ++d) wx[d] = Wx[d * G4 + tid];
    const float bj = bias[tid];
    if (tid < Hh) h_lds[tid] = 0.0f;
    for (int i = tid; i < Cc * Hh; i += 1024) wout_t[i % Cc][i / Cc] = Wout[i];
    if (tid < Cc) bout_l[tid] = bout[tid];
    const float* xB = x + (long)b * Tt * Dd;
    if (tid < Dd) x_lds[0][tid] = xB[tid];
    float c_state = 0.0f;
    __syncthreads();
    const float* WhB = Wh + tid;
    for (int t = 0; t < Tt; ++t) {
        float gg = bj;
        const float* xr = x_lds[t & 1];
        #pragma unroll
        for (int d = 0; d < Dd; ++d) gg += xr[d] * wx[d];
        #pragma unroll 8
        for (int k = 0; k < Hh; ++k) gg += h_lds[k] * WhB[k * G4];
        float a;
        if (tid < 2 * Hh)      a = 1.0f / (1.0f + expf(-gg));
        else if (tid < 3 * Hh) a = tanhf(gg);
        else                   a = 1.0f / (1.0f + expf(-gg));
        gates_lds[tid] = a;
        __syncthreads();
        if (tid < Hh) {
            float iv = gates_lds[tid], fv = gates_lds[tid + Hh];
            float gv = gates_lds[tid + 2 * Hh], ov = gates_lds[tid + 3 * Hh];
            c_state = fv * c_state + iv * gv;
            h_lds[tid] = ov * tanhf(c_state);
        } else if (tid >= 384 && tid < 448) {
            int tn = t + 1;
            if (tn < Tt) x_lds[tn & 1][tid - 384] = xB[(long)tn * Dd + (tid - 384)];
        }
        __syncthreads();
        const int w = tid >> 6, l = tid & 63;
        if (w < Cc) {
            float p = 0.0f;
            #pragma unroll
            for (int qq = 0; qq < 4; ++qq) p += h_lds[l + 64 * qq] * wout_t[w][l + 64 * qq];
            #pragma unroll
            for (int off = 32; off > 0; off >>= 1) p += __shfl_down(p, off);
            if (l == 0) out[((long)b * Tt + t) * Cc + w] = p + bout_l[w];
        }
    }
}

extern "C" void kernel_launch(void* const* d_in, const int* in_sizes, int n_in,
                              void* d_out, int out_size, void* d_ws, size_t ws_size,
                              hipStream_t stream) {
    const float* x    = (const float*)d_in[0];
    const float* Wx   = (const float*)d_in[1];
    const float* Wh   = (const float*)d_in[2];
    const float* bvec = (const float*)d_in[3];
    const float* Wout = (const float*)d_in[4];
    const float* bout = (const float*)d_in[5];
    float* outp = (float*)d_out;

    if (ws_size >= XG_BYTES) {
        unsigned short* xgws = (unsigned short*)d_ws;
        xg_gemm<<<dim3(BT / 64, 4), dim3(256), 0, stream>>>(x, Wx, bvec, xgws);
        lstm_xg<<<dim3(128), dim3(256), 0, stream>>>(xgws, Wh);
        out_proj<<<dim3(128, 4), dim3(256), 0, stream>>>(xgws, Wout, bout, outp);
    } else {
        lstm_fused<<<dim3(128), dim3(1024), 0, stream>>>(x, Wx, Wh, bvec, Wout, bout, outp);
    }
}